// Round 5
// baseline (461.130 us; speedup 1.0000x reference)
//
#include <hip/hip_runtime.h>
#include <hip/hip_fp16.h>
#include <type_traits>

#define NN 10000
#define EE 160000

typedef _Float16 half8 __attribute__((ext_vector_type(8)));
typedef float    f32x4 __attribute__((ext_vector_type(4)));

// ---------------------------------------------------------------------------
// Node phase (split into 3 for MFMA):
//  pre : Xt[(n,ij)][c] fp16  <- X[n][c][ij] f32      (pack/transpose)
//  gemm: Xp[(n,ij)][o] = sum_c Xt * Wp[o][c] + bp[o] (k_gemm_mfma)
//  post: per (n,o): norm over 9 ij, decompose -> Xn[n][o][ij], D1[n][10][128]
// ---------------------------------------------------------------------------
__global__ __launch_bounds__(256) void k_node_pre(
    const float* __restrict__ X, _Float16* __restrict__ Xt)
{
  __shared__ float Xl[4*1152];
  const int n0 = blockIdx.x * 4;
  const int t = threadIdx.x;
  const float* src = X + (size_t)n0*1152;
  #pragma unroll
  for (int idx = t; idx < 4*1152; idx += 256) Xl[idx] = src[idx];
  __syncthreads();
  _Float16* dst = Xt + (size_t)n0*1152;
  #pragma unroll
  for (int idx = t; idx < 4*1152; idx += 256) {
    int node = idx / 1152, rem = idx - node*1152;
    int ij = rem >> 7, c = rem & 127;
    dst[idx] = (_Float16)Xl[node*1152 + c*9 + ij];   // stride-9 LDS: odd -> conflict-free
  }
}

__global__ __launch_bounds__(256) void k_node_post(
    const _Float16* __restrict__ Xp,
    __half* __restrict__ Xn, __half* __restrict__ D1)
{
  int idx = blockIdx.x*256 + threadIdx.x;
  int n = idx >> 7, o = idx & 127;
  float m[9], ss = 0.f;
  #pragma unroll
  for (int ij = 0; ij < 9; ++ij) {
    m[ij] = (float)Xp[((size_t)n*9 + ij)*128 + o];   // coalesced across o
    ss += m[ij]*m[ij];
  }
  ss = fmaxf(ss, 0.01f);
  float inv = 1.f / (ss + 1.f);
  #pragma unroll
  for (int ij = 0; ij < 9; ++ij) m[ij] *= inv;
  __half* xo = &Xn[(size_t)n*1152 + o*9];
  #pragma unroll
  for (int ij = 0; ij < 9; ++ij) xo[ij] = __float2half(m[ij]);
  float lam = (m[0]+m[4]+m[8]) * (1.f/3.f);
  __half* Dn = &D1[(size_t)n*1280];
  Dn[0*128+o] = __float2half(lam);
  Dn[1*128+o] = __float2half(0.5f*(m[1]-m[3]));
  Dn[2*128+o] = __float2half(0.5f*(m[2]-m[6]));
  Dn[3*128+o] = __float2half(0.5f*(m[5]-m[7]));
  Dn[4*128+o] = __float2half(m[0]-lam);
  Dn[5*128+o] = __float2half(0.5f*(m[1]+m[3]));
  Dn[6*128+o] = __float2half(0.5f*(m[2]+m[6]));
  Dn[7*128+o] = __float2half(m[4]-lam);
  Dn[8*128+o] = __float2half(0.5f*(m[5]+m[7]));
  Dn[9*128+o] = __float2half(m[8]-lam);
}

// ---------------------------------------------------------------------------
// MFMA GEMM: C[m][n] = post( sum_k A[m][k] * W[n][k] + bias[n] )
//   - mfma_f32_16x16x32_f16, fp32 accumulate
//   - 256 thr = 4 waves; BM=256 (wave w owns rows w*64..w*64+63), BN=64
//   - wave fragment-repeat acc[4][4] (4 row-frags x 4 col-frags of 16)
//   - A frags from global (16B/lane, hoisted row ptrs); W staged fp32->fp16
//     into FRAGMENT-LINEAR LDS: Bs[g][lane][8], g = (k0/32)*4 + colfrag.
//     K-loop read = Bs + g*1024B + lane*16B  -> conflict-free b128 (r4 fix:
//     old pitch gave row stride ≡ 4 banks -> 8-way conflict, 3.8e6/dispatch)
//   - XCD-bijective swizzle (m204), n-tile fastest => A m-panel L2-resident
//   - PSEL: blockIdx.z = p in 0..9: W = p==0?W0 : p<4?W1 : W2; A,C col-offset p*128
// ---------------------------------------------------------------------------
template<typename TA, int KT, bool ACT, bool CUT, bool PSEL>
__global__ __launch_bounds__(256) void k_gemm_mfma(
    const TA* __restrict__ A, int lda,
    const float* __restrict__ W0, const float* __restrict__ W1, const float* __restrict__ W2,
    const float* __restrict__ bias, const float* __restrict__ cw,
    _Float16* __restrict__ C, int ldc,
    int M, int nTiles)
{
  constexpr int NFRAG = (KT/32)*4;          // fragment groups
  __shared__ _Float16 Bs[NFRAG*64*8];       // [g][lane][8]
  const int t = threadIdx.x;

  // XCD-bijective block swizzle (m204): each XCD gets a contiguous chunk.
  int nwg = gridDim.x;
  int bid = blockIdx.x;
  int q = nwg >> 3, rr = nwg & 7;
  int xcd = bid & 7, ii = bid >> 3;
  int swz = (xcd < rr) ? xcd*(q+1) + ii : rr*(q+1) + (xcd-rr)*q + ii;
  int nt = swz % nTiles;
  int mt = swz / nTiles;

  const float* W = W0;
  int coff = 0;
  if (PSEL) {
    int p = blockIdx.z;
    W = (p == 0) ? W0 : (p < 4 ? W1 : W2);
    coff = p * 128;
  }
  const int n0 = nt * 64;
  const int m0 = mt * 256;

  // stage W strip [64][KT] fp32 -> fp16 fragment-linear LDS
  #pragma unroll
  for (int u = t; u < NFRAG*64; u += 256) {
    int g = u >> 6, lu = u & 63;
    int lru = lu & 15, lqu = lu >> 4;
    int nn = (g & 3)*16 + lru;
    int kk = (g >> 2)*32 + lqu*8;
    const float* wp = &W[(size_t)(n0 + nn)*KT + kk];
    f32x4 w0 = *reinterpret_cast<const f32x4*>(wp);
    f32x4 w1 = *reinterpret_cast<const f32x4*>(wp + 4);
    half8 hv;
    #pragma unroll
    for (int j = 0; j < 4; ++j) { hv[j] = (_Float16)w0[j]; hv[4+j] = (_Float16)w1[j]; }
    *reinterpret_cast<half8*>(&Bs[u*8]) = hv;
  }
  __syncthreads();

  const int wave = t >> 6, lane = t & 63;
  const int lr = lane & 15, lq = lane >> 4;
  const int rowBase = m0 + wave*64;
  const int kBase = lq*8;

  // hoist A row pointers (clamped)
  const TA* aptr[4];
  #pragma unroll
  for (int r = 0; r < 4; ++r) {
    int gm = rowBase + r*16 + lr;
    if (gm > M-1) gm = M-1;
    aptr[r] = A + (size_t)gm*lda + coff + kBase;
  }

  f32x4 acc[4][4] = {};
  #pragma unroll
  for (int k0 = 0; k0 < KT; k0 += 32) {
    half8 b[4];
    #pragma unroll
    for (int c = 0; c < 4; ++c)
      b[c] = *reinterpret_cast<const half8*>(&Bs[(((k0>>5)<<2) + c)*512 + lane*8]);
    half8 a[4];
    #pragma unroll
    for (int r = 0; r < 4; ++r) {
      const TA* ap = aptr[r] + k0;
      if constexpr (std::is_same<TA, float>::value) {
        f32x4 u0 = *reinterpret_cast<const f32x4*>(ap);
        f32x4 u1 = *reinterpret_cast<const f32x4*>(ap + 4);
        half8 av;
        #pragma unroll
        for (int j = 0; j < 4; ++j) { av[j] = (_Float16)u0[j]; av[4+j] = (_Float16)u1[j]; }
        a[r] = av;
      } else {
        a[r] = *reinterpret_cast<const half8*>(ap);
      }
    }
    #pragma unroll
    for (int r = 0; r < 4; ++r)
      #pragma unroll
      for (int c = 0; c < 4; ++c)
        acc[r][c] = __builtin_amdgcn_mfma_f32_16x16x32_f16(a[r], b[c], acc[r][c], 0, 0, 0);
  }

  // epilogue
  float bvv[4];
  #pragma unroll
  for (int c = 0; c < 4; ++c)
    bvv[c] = bias ? bias[n0 + c*16 + lr] : 0.f;
  #pragma unroll
  for (int r = 0; r < 4; ++r) {
    #pragma unroll
    for (int j = 0; j < 4; ++j) {
      int gm = rowBase + r*16 + lq*4 + j;   // C/D: col=lane&15, row=(lane>>4)*4+reg
      if (gm >= M) continue;
      float Cf = 1.f;
      if (CUT) {
        float wv = cw[gm];
        Cf = (wv < 5.f) ? 0.5f*(__cosf(wv*0.62831853071795864769f) + 1.f) : 0.f;
      }
      _Float16* crow = C + (size_t)gm*ldc + coff + n0;
      #pragma unroll
      for (int c = 0; c < 4; ++c) {
        float v = acc[r][c][j] + bvv[c];
        if (ACT) v = v / (1.f + __expf(-v));   // silu
        if (CUT) v *= Cf;
        crow[c*16 + lr] = (_Float16)v;
      }
    }
  }
}

// ---------------------------------------------------------------------------
// CSR build over src
// ---------------------------------------------------------------------------
__global__ void k_zero_i(int* __restrict__ p, int n) {
  int i = blockIdx.x*256 + threadIdx.x;
  if (i < n) p[i] = 0;
}
__global__ void k_hist(const int* __restrict__ src, int* __restrict__ cnt) {
  int e = blockIdx.x*256 + threadIdx.x;
  if (e < EE) atomicAdd(&cnt[src[e]], 1);
}
__global__ __launch_bounds__(1024) void k_scan(const int* __restrict__ cnt,
                                               int* __restrict__ off,
                                               int* __restrict__ cur) {
  __shared__ int s[1024];
  __shared__ int carry;
  int t = threadIdx.x;
  if (t == 0) carry = 0;
  __syncthreads();
  for (int base = 0; base < NN; base += 1024) {
    int i = base + t;
    int v = (i < NN) ? cnt[i] : 0;
    s[t] = v; __syncthreads();
    for (int d = 1; d < 1024; d <<= 1) {
      int x = (t >= d) ? s[t-d] : 0; __syncthreads();
      s[t] += x; __syncthreads();
    }
    int incl = s[t];
    int total = s[1023];
    int excl = incl - v + carry;
    if (i < NN) { off[i] = excl; cur[i] = excl; }
    __syncthreads();
    if (t == 0) carry += total;
    __syncthreads();
  }
  if (t == 0) off[NN] = carry;
}
__global__ void k_scatter(const int* __restrict__ src, int* __restrict__ cur,
                          int* __restrict__ elist) {
  int e = blockIdx.x*256 + threadIdx.x;
  if (e < EE) { int pos = atomicAdd(&cur[src[e]], 1); elist[pos] = e; }
}

// ---------------------------------------------------------------------------
// Message passing: one block per node; decomposed accumulation (I:1,A:3,S:6).
// ea already includes the cutoff factor.
// ---------------------------------------------------------------------------
__global__ __launch_bounds__(256) void k_message(
    const __half* __restrict__ ea, const __half* __restrict__ T1,
    const int* __restrict__ dstArr,
    const int* __restrict__ off, const int* __restrict__ elist,
    __half* __restrict__ msg)
{
  int n = blockIdx.x;
  int t = threadIdx.x;
  int o = t & 127, ph = t >> 7;
  int e0 = off[n], e1 = off[n+1];
  float acc0=0.f, acc1=0.f, acc2=0.f, acc3=0.f, acc4=0.f;
  for (int ii = e0; ii < e1; ++ii) {
    int e = elist[ii];
    int d = dstArr[e];
    const __half* he = &ea[(size_t)e*384 + 3*o];
    const __half* Td = &T1[(size_t)d*1280 + o];
    if (ph == 0) {
      float f0 = (float)he[0];
      float f1 = (float)he[1];
      float f2 = (float)he[2];
      acc0 += f0 * (float)Td[0];      // lam'
      acc1 += f1 * (float)Td[128];    // a0'
      acc2 += f1 * (float)Td[256];    // a1'
      acc3 += f1 * (float)Td[384];    // a2'
      acc4 += f2 * (float)Td[512];    // s00'
    } else {
      float f2 = (float)he[2];
      acc0 += f2 * (float)Td[640];    // s01'
      acc1 += f2 * (float)Td[768];    // s02'
      acc2 += f2 * (float)Td[896];    // s11'
      acc3 += f2 * (float)Td[1024];   // s12'
      acc4 += f2 * (float)Td[1152];   // s22'
    }
  }
  __half* mn = &msg[(size_t)n*1280 + o];
  int pb = ph * 5;
  mn[(pb+0)*128] = __float2half(acc0);
  mn[(pb+1)*128] = __float2half(acc1);
  mn[(pb+2)*128] = __float2half(acc2);
  mn[(pb+3)*128] = __float2half(acc3);
  mn[(pb+4)*128] = __float2half(acc4);
}

// ---------------------------------------------------------------------------
// Bracket: B = M*Y + Y*M ; decompose ; /(tnorm(B)+1) -> D2
// D2 may alias T1 (in-place): no __restrict__ on those params.
// ---------------------------------------------------------------------------
__global__ __launch_bounds__(256) void k_bracket(
    const __half* __restrict__ msgp, const __half* T1, __half* D2)
{
  int idx = blockIdx.x*256 + threadIdx.x;
  int n = idx >> 7, o = idx & 127;
  const __half* Mc = &msgp[(size_t)n*1280 + o];
  const __half* Yc = &T1[(size_t)n*1280 + o];
  float Mm[9], Ym[9];
  {
    float lam=(float)Mc[0], a0=(float)Mc[128], a1=(float)Mc[256], a2=(float)Mc[384];
    float s00=(float)Mc[512], s01=(float)Mc[640], s02=(float)Mc[768];
    float s11=(float)Mc[896], s12=(float)Mc[1024], s22=(float)Mc[1152];
    Mm[0]=lam+s00; Mm[1]=a0+s01;  Mm[2]=a1+s02;
    Mm[3]=s01-a0;  Mm[4]=lam+s11; Mm[5]=a2+s12;
    Mm[6]=s02-a1;  Mm[7]=s12-a2;  Mm[8]=lam+s22;
  }
  {
    float lam=(float)Yc[0], a0=(float)Yc[128], a1=(float)Yc[256], a2=(float)Yc[384];
    float s00=(float)Yc[512], s01=(float)Yc[640], s02=(float)Yc[768];
    float s11=(float)Yc[896], s12=(float)Yc[1024], s22=(float)Yc[1152];
    Ym[0]=lam+s00; Ym[1]=a0+s01;  Ym[2]=a1+s02;
    Ym[3]=s01-a0;  Ym[4]=lam+s11; Ym[5]=a2+s12;
    Ym[6]=s02-a1;  Ym[7]=s12-a2;  Ym[8]=lam+s22;
  }
  float B[9];
  #pragma unroll
  for (int i = 0; i < 3; ++i) {
    #pragma unroll
    for (int j = 0; j < 3; ++j) {
      float s = 0.f;
      #pragma unroll
      for (int k = 0; k < 3; ++k)
        s += Mm[i*3+k]*Ym[k*3+j] + Ym[i*3+k]*Mm[k*3+j];
      B[i*3+j] = s;
    }
  }
  float lamb = (B[0]+B[4]+B[8]) * (1.f/3.f);
  float ss = 0.f;
  #pragma unroll
  for (int qq = 0; qq < 9; ++qq) ss += B[qq]*B[qq];
  float inv = 1.f / (fmaxf(ss, 0.01f) + 1.f);
  __half* Dn = &D2[(size_t)n*1280 + o];
  Dn[0]    = __float2half(lamb*inv);
  Dn[128]  = __float2half(0.5f*(B[1]-B[3])*inv);
  Dn[256]  = __float2half(0.5f*(B[2]-B[6])*inv);
  Dn[384]  = __float2half(0.5f*(B[5]-B[7])*inv);
  Dn[512]  = __float2half((B[0]-lamb)*inv);
  Dn[640]  = __float2half(0.5f*(B[1]+B[3])*inv);
  Dn[768]  = __float2half(0.5f*(B[2]+B[6])*inv);
  Dn[896]  = __float2half((B[4]-lamb)*inv);
  Dn[1024] = __float2half(0.5f*(B[5]+B[7])*inv);
  Dn[1152] = __float2half((B[8]-lamb)*inv);
}

// ---------------------------------------------------------------------------
// Final: out = Xn + reconstruct(Tb)
// ---------------------------------------------------------------------------
__global__ __launch_bounds__(256) void k_final(
    const __half* __restrict__ Xn, const __half* __restrict__ Tb,
    float* __restrict__ out)
{
  int idx = blockIdx.x*256 + threadIdx.x;
  int n = idx >> 7, o = idx & 127;
  const __half* Tc = &Tb[(size_t)n*1280 + o];
  float lam=(float)Tc[0], a0=(float)Tc[128], a1=(float)Tc[256], a2=(float)Tc[384];
  float s00=(float)Tc[512], s01=(float)Tc[640], s02=(float)Tc[768];
  float s11=(float)Tc[896], s12=(float)Tc[1024], s22=(float)Tc[1152];
  const __half* xc = &Xn[(size_t)n*1152 + o*9];
  float* oc = &out[(size_t)n*1152 + o*9];
  oc[0] = (float)xc[0] + lam + s00;
  oc[1] = (float)xc[1] + a0  + s01;
  oc[2] = (float)xc[2] + a1  + s02;
  oc[3] = (float)xc[3] - a0  + s01;
  oc[4] = (float)xc[4] + lam + s11;
  oc[5] = (float)xc[5] + a2  + s12;
  oc[6] = (float)xc[6] - a1  + s02;
  oc[7] = (float)xc[7] - a2  + s12;
  oc[8] = (float)xc[8] + lam + s22;
}

// ---------------------------------------------------------------------------
extern "C" void kernel_launch(void* const* d_in, const int* in_sizes, int n_in,
                              void* d_out, int out_size, void* d_ws, size_t ws_size,
                              hipStream_t stream)
{
  const float* X     = (const float*)d_in[0];
  const float* ew    = (const float*)d_in[1];
  const float* eattr = (const float*)d_in[2];
  const float* Wp    = (const float*)d_in[3];
  const float* bp    = (const float*)d_in[4];
  const float* Ws0   = (const float*)d_in[5];
  const float* bs0   = (const float*)d_in[6];
  const float* Ws1   = (const float*)d_in[7];
  const float* bs1   = (const float*)d_in[8];
  const float* Ws2   = (const float*)d_in[9];
  const float* bs2   = (const float*)d_in[10];
  const int*   eidx  = (const int*)d_in[11];
  const float* Wt0   = (const float*)d_in[12];
  const float* Wt1   = (const float*)d_in[13];
  const float* Wt2   = (const float*)d_in[14];
  const float* Wt3   = (const float*)d_in[15];
  const float* Wt4   = (const float*)d_in[16];
  const float* Wt5   = (const float*)d_in[17];
  float* out = (float*)d_out;

  // Packed lifetime-aliased layout, peak 254,161,920 B:
  //  A [0,          23,040,000)  Xn fp16                  [node_post -> final]
  //  B [23,040,000, 48,640,000)  T1 fp16 -> D2 (in-place) [K2 -> K4]
  //  C [48,640,000, 130,560,000) {D1 | Xt | Xp} -> h1 -> msg -> Tb
  //  D [130,560,000,253,440,000) h0 -> ea                 (122.88 MB)
  //  csr [253,440,000, 254,161,920)
  const size_t NEED = 254161920;
  if (ws_size < NEED) return;   // diagnostic: poison-fail instead of fault

  char* base = (char*)d_ws;
  __half*   Xn  = (__half*)(base);
  __half*   T1  = (__half*)(base + 23040000);
  __half*   D1  = (__half*)(base + 48640000);          // 25.6 MB [node_post -> K2]
  _Float16* Xt  = (_Float16*)(base + 74240000);        // 23.04 MB [pre -> gemm]
  _Float16* Xp  = (_Float16*)(base + 97280000);        // 23.04 MB [gemm -> post]
  __half*   h1  = (__half*)(base + 48640000);
  __half*   msg = (__half*)(base + 48640000);
  __half*   Tb  = (__half*)(base + 48640000);
  __half*   h0  = (__half*)(base + 130560000);
  __half*   ea  = (__half*)(base + 130560000);
  char*     csr = base + 253440000;
  int* off_  = (int*)csr;
  int* cur_  = (int*)(csr + 40960);
  int* elist = (int*)(csr + 81920);

  (void)in_sizes; (void)n_in; (void)out_size;

  // node phase: pack -> MFMA GEMM (M=90000,K=128,N=128, bias=bp) -> norm/decompose
  k_node_pre<<<2500, 256, 0, stream>>>(X, Xt);
  k_gemm_mfma<_Float16, 128, false, false, false><<<dim3(352*2, 1, 1), 256, 0, stream>>>(
      Xt, 128, Wp, nullptr, nullptr, bp, nullptr, Xp, 128, 9*NN, 2);
  k_node_post<<<5000, 256, 0, stream>>>(Xp, Xn, D1);

  // T' = clin(I,Wt0)/clin(A,Wt1)/clin(S,Wt2): 10 slices of [10000 x 128 x 128]
  k_gemm_mfma<_Float16, 128, false, false, true><<<dim3(40*2, 1, 10), 256, 0, stream>>>(
      (_Float16*)D1, 1280, Wt0, Wt1, Wt2, nullptr, nullptr, (_Float16*)T1, 1280, NN, 2);

  // edge MLP (cutoff folded into last layer's epilogue)
  k_gemm_mfma<float, 32, true, false, false><<<dim3(625*2, 1, 1), 256, 0, stream>>>(
      eattr, 32, Ws0, nullptr, nullptr, bs0, nullptr, (_Float16*)h0, 128, EE, 2);
  k_gemm_mfma<_Float16, 128, true, false, false><<<dim3(625*4, 1, 1), 256, 0, stream>>>(
      (_Float16*)h0, 128, Ws1, nullptr, nullptr, bs1, nullptr, (_Float16*)h1, 256, EE, 4);
  k_gemm_mfma<_Float16, 256, true, true, false><<<dim3(625*6, 1, 1), 256, 0, stream>>>(
      (_Float16*)h1, 256, Ws2, nullptr, nullptr, bs2, ew, (_Float16*)ea, 384, EE, 6);

  // CSR over src
  k_zero_i<<<40, 256, 0, stream>>>(cur_, NN);
  k_hist<<<625, 256, 0, stream>>>(eidx, cur_);
  k_scan<<<1, 1024, 0, stream>>>(cur_, off_, cur_);
  k_scatter<<<625, 256, 0, stream>>>(eidx, cur_, elist);

  // message passing (gather T'[dst], reduce per src node)
  k_message<<<NN, 256, 0, stream>>>(ea, T1, eidx + EE, off_, elist, msg);

  // bracket + decompose + norm (D2 overwrites T1 in-place)
  k_bracket<<<5000, 256, 0, stream>>>(msg, T1, T1);

  // dX components = clin with Wt3/4/5
  k_gemm_mfma<_Float16, 128, false, false, true><<<dim3(40*2, 1, 10), 256, 0, stream>>>(
      (_Float16*)T1, 1280, Wt3, Wt4, Wt5, nullptr, nullptr, (_Float16*)Tb, 1280, NN, 2);

  // out = Xn + reconstruct(dX)
  k_final<<<5000, 256, 0, stream>>>(Xn, Tb, out);
}

// Round 6
// 407.243 us; speedup vs baseline: 1.1323x; 1.1323x over previous
//
#include <hip/hip_runtime.h>
#include <hip/hip_fp16.h>
#include <type_traits>

#define NN 10000
#define EE 160000

typedef _Float16 half8 __attribute__((ext_vector_type(8)));
typedef float    f32x4 __attribute__((ext_vector_type(4)));

// ---------------------------------------------------------------------------
// Node phase (split into 3 for MFMA):
//  pre : Xt[(n,ij)][c] fp16  <- X[n][c][ij] f32      (pack/transpose)
//  gemm: Xp[(n,ij)][o] = sum_c Xt * Wp[o][c] + bp[o] (k_gemm_mfma)
//  post: per (n,o): norm over 9 ij, decompose -> Xn[n][o][ij], D1[n][10][128]
// ---------------------------------------------------------------------------
__global__ __launch_bounds__(256) void k_node_pre(
    const float* __restrict__ X, _Float16* __restrict__ Xt)
{
  __shared__ float Xl[4*1152];
  const int n0 = blockIdx.x * 4;
  const int t = threadIdx.x;
  const float* src = X + (size_t)n0*1152;
  #pragma unroll
  for (int idx = t; idx < 4*1152; idx += 256) Xl[idx] = src[idx];
  __syncthreads();
  _Float16* dst = Xt + (size_t)n0*1152;
  #pragma unroll
  for (int idx = t; idx < 4*1152; idx += 256) {
    int node = idx / 1152, rem = idx - node*1152;
    int ij = rem >> 7, c = rem & 127;
    dst[idx] = (_Float16)Xl[node*1152 + c*9 + ij];   // stride-9 LDS: odd -> conflict-free
  }
}

__global__ __launch_bounds__(256) void k_node_post(
    const _Float16* __restrict__ Xp,
    __half* __restrict__ Xn, __half* __restrict__ D1)
{
  int idx = blockIdx.x*256 + threadIdx.x;
  int n = idx >> 7, o = idx & 127;
  float m[9], ss = 0.f;
  #pragma unroll
  for (int ij = 0; ij < 9; ++ij) {
    m[ij] = (float)Xp[((size_t)n*9 + ij)*128 + o];   // coalesced across o
    ss += m[ij]*m[ij];
  }
  ss = fmaxf(ss, 0.01f);
  float inv = 1.f / (ss + 1.f);
  #pragma unroll
  for (int ij = 0; ij < 9; ++ij) m[ij] *= inv;
  __half* xo = &Xn[(size_t)n*1152 + o*9];
  #pragma unroll
  for (int ij = 0; ij < 9; ++ij) xo[ij] = __float2half(m[ij]);
  float lam = (m[0]+m[4]+m[8]) * (1.f/3.f);
  __half* Dn = &D1[(size_t)n*1280];
  Dn[0*128+o] = __float2half(lam);
  Dn[1*128+o] = __float2half(0.5f*(m[1]-m[3]));
  Dn[2*128+o] = __float2half(0.5f*(m[2]-m[6]));
  Dn[3*128+o] = __float2half(0.5f*(m[5]-m[7]));
  Dn[4*128+o] = __float2half(m[0]-lam);
  Dn[5*128+o] = __float2half(0.5f*(m[1]+m[3]));
  Dn[6*128+o] = __float2half(0.5f*(m[2]+m[6]));
  Dn[7*128+o] = __float2half(m[4]-lam);
  Dn[8*128+o] = __float2half(0.5f*(m[5]+m[7]));
  Dn[9*128+o] = __float2half(m[8]-lam);
}

// ---------------------------------------------------------------------------
// Weight pre-pack: W [N][K] f32 -> fragment-linear fp16
//   Wfl[((kc*(N/16) + nf)*64 + lane)*8 + j] = W[nf*16 + (lane&15)][kc*32 + (lane>>4)*8 + j]
// so that staging chunk (kc, nt) is 8KB CONTIGUOUS and b-frag reads are lane*16B.
// ---------------------------------------------------------------------------
__global__ __launch_bounds__(256) void k_wprep(
    const float* __restrict__ W, _Float16* __restrict__ Wfl, int N, int K)
{
  int u = blockIdx.x*256 + threadIdx.x;
  int total = (N >> 4) * (K >> 5) * 64;
  if (u >= total) return;
  int lane = u & 63, rest = u >> 6;
  int nfTotal = N >> 4;
  int nf = rest % nfTotal, kc = rest / nfTotal;
  int n = nf*16 + (lane & 15);
  int k = kc*32 + (lane >> 4)*8;
  const float* src = W + (size_t)n*K + k;
  half8 hv;
  #pragma unroll
  for (int j = 0; j < 8; ++j) hv[j] = (_Float16)src[j];
  *reinterpret_cast<half8*>(Wfl + (size_t)u*8) = hv;
}

// ---------------------------------------------------------------------------
// Pipelined MFMA GEMM (m97 structure): C[m][n] = post(sum_k A[m][k]*W[n][k]+b[n])
//   - BM=128, BN=128, BK=32, 4 waves; wave owns 32 rows x 128 cols (acc[2][8])
//   - A and W double-buffered in LDS via global_load_lds width-16 DMA
//   - A LDS [row][4 segs of 8h], source pre-swizzled seg^(row&3); read at
//     seg = lq^(lr&3)  -> all 64 lanes balanced 8-per-bank-quad (conflict-free)
//   - W from frag-linear fp16 (k_wprep): linear DMA, reads lane*16B contiguous
//   - 2-phase/chunk: stage(kc+1) || ds_read+MFMA(kc); one __syncthreads/chunk
//     (its vmcnt/lgkm drain is the m97 structural stall - accepted)
//   - requires lda == KT and M % 128 == 0 (holds for edge MLP: 160000, 128/256)
// ---------------------------------------------------------------------------
template<int KT, bool ACT, bool CUT>
__global__ __launch_bounds__(256, 4) void k_gemm_pipe(
    const _Float16* __restrict__ A,
    const _Float16* __restrict__ Wfl,
    const float* __restrict__ bias, const float* __restrict__ cw,
    _Float16* __restrict__ C, int ldc,
    int M, int nTiles)
{
  constexpr int NC = KT / 32;
  __shared__ _Float16 Abuf[2][128*32];
  __shared__ _Float16 Wbuf[2][128*32];
  const int t = threadIdx.x;
  const int nfTotal = nTiles * 8;

  // XCD-bijective block swizzle (m204), n-tile fastest
  int nwg = gridDim.x, bid = blockIdx.x;
  int q = nwg >> 3, rr = nwg & 7;
  int xcd = bid & 7, ii = bid >> 3;
  int swz = (xcd < rr) ? xcd*(q+1) + ii : rr*(q+1) + (xcd-rr)*q + ii;
  int nt = swz % nTiles, mt = swz / nTiles;
  const int n0 = nt * 128, m0 = mt * 128;

  auto stage = [&](int d, int kc) {
    #pragma unroll
    for (int i = 0; i < 2; ++i) {
      int u = t + i*256;
      int row = u >> 2, seg = u & 3;
      int gm = m0 + row; if (gm > M-1) gm = M-1;
      const _Float16* gp = A + (size_t)gm*KT + kc*32 + ((seg ^ (row & 3)) << 3);
      __builtin_amdgcn_global_load_lds(
          (const __attribute__((address_space(1))) _Float16*)gp,
          (__attribute__((address_space(3))) _Float16*)(&Abuf[d][u*8]), 16, 0, 0);
    }
    const _Float16* wp = Wfl + (((size_t)kc*nfTotal + nt*8) << 9);
    #pragma unroll
    for (int i = 0; i < 2; ++i) {
      int u = t + i*256;
      __builtin_amdgcn_global_load_lds(
          (const __attribute__((address_space(1))) _Float16*)(wp + u*8),
          (__attribute__((address_space(3))) _Float16*)(&Wbuf[d][u*8]), 16, 0, 0);
    }
  };

  const int wave = t >> 6, lane = t & 63;
  const int lr = lane & 15, lq = lane >> 4;
  const int wrow = wave * 32;
  const int aoff = (lq ^ (lr & 3)) << 3;   // swizzled seg (row&3 == lr&3 here)

  f32x4 acc[2][8] = {};

  stage(0, 0);
  __syncthreads();
  int cur = 0;
  for (int kc = 0; kc < NC; ++kc) {
    if (kc + 1 < NC) stage(cur ^ 1, kc + 1);
    const _Float16* ab = &Abuf[cur][0];
    const _Float16* wb = &Wbuf[cur][0];
    half8 a0 = *reinterpret_cast<const half8*>(ab + (wrow + lr)*32 + aoff);
    half8 a1 = *reinterpret_cast<const half8*>(ab + (wrow + 16 + lr)*32 + aoff);
    #pragma unroll
    for (int c = 0; c < 8; ++c) {
      half8 b = *reinterpret_cast<const half8*>(wb + c*512 + lane*8);
      acc[0][c] = __builtin_amdgcn_mfma_f32_16x16x32_f16(a0, b, acc[0][c], 0, 0, 0);
      acc[1][c] = __builtin_amdgcn_mfma_f32_16x16x32_f16(a1, b, acc[1][c], 0, 0, 0);
    }
    if (kc + 1 < NC) { __syncthreads(); cur ^= 1; }
  }

  // epilogue
  float bvv[8];
  #pragma unroll
  for (int c = 0; c < 8; ++c) bvv[c] = bias[n0 + c*16 + lr];
  #pragma unroll
  for (int r = 0; r < 2; ++r) {
    #pragma unroll
    for (int j = 0; j < 4; ++j) {
      int gm = m0 + wrow + r*16 + lq*4 + j;   // C/D: col=lane&15, row=(lane>>4)*4+reg
      if (gm >= M) continue;
      float Cf = 1.f;
      if (CUT) {
        float wv = cw[gm];
        Cf = (wv < 5.f) ? 0.5f*(__cosf(wv*0.62831853071795864769f) + 1.f) : 0.f;
      }
      _Float16* crow = C + (size_t)gm*ldc + n0;
      #pragma unroll
      for (int c = 0; c < 8; ++c) {
        float v = acc[r][c][j] + bvv[c];
        if (ACT) v = v / (1.f + __expf(-v));   // silu
        if (CUT) v *= Cf;
        crow[c*16 + lr] = (_Float16)v;
      }
    }
  }
}

// ---------------------------------------------------------------------------
// MFMA GEMM (non-pipelined; used for small/odd-shaped GEMMs):
//   BM=256, BN=64; W staged fp32->fp16 fragment-linear LDS (conflict-free)
//   PSEL: blockIdx.z = p in 0..9: W = p==0?W0 : p<4?W1 : W2; A,C col-offset p*128
// ---------------------------------------------------------------------------
template<typename TA, int KT, bool ACT, bool CUT, bool PSEL>
__global__ __launch_bounds__(256) void k_gemm_mfma(
    const TA* __restrict__ A, int lda,
    const float* __restrict__ W0, const float* __restrict__ W1, const float* __restrict__ W2,
    const float* __restrict__ bias, const float* __restrict__ cw,
    _Float16* __restrict__ C, int ldc,
    int M, int nTiles)
{
  constexpr int NFRAG = (KT/32)*4;          // fragment groups
  __shared__ _Float16 Bs[NFRAG*64*8];       // [g][lane][8]
  const int t = threadIdx.x;

  int nwg = gridDim.x;
  int bid = blockIdx.x;
  int q = nwg >> 3, rr = nwg & 7;
  int xcd = bid & 7, ii = bid >> 3;
  int swz = (xcd < rr) ? xcd*(q+1) + ii : rr*(q+1) + (xcd-rr)*q + ii;
  int nt = swz % nTiles;
  int mt = swz / nTiles;

  const float* W = W0;
  int coff = 0;
  if (PSEL) {
    int p = blockIdx.z;
    W = (p == 0) ? W0 : (p < 4 ? W1 : W2);
    coff = p * 128;
  }
  const int n0 = nt * 64;
  const int m0 = mt * 256;

  // stage W strip [64][KT] fp32 -> fp16 fragment-linear LDS
  #pragma unroll
  for (int u = t; u < NFRAG*64; u += 256) {
    int g = u >> 6, lu = u & 63;
    int lru = lu & 15, lqu = lu >> 4;
    int nn = (g & 3)*16 + lru;
    int kk = (g >> 2)*32 + lqu*8;
    const float* wp = &W[(size_t)(n0 + nn)*KT + kk];
    f32x4 w0 = *reinterpret_cast<const f32x4*>(wp);
    f32x4 w1 = *reinterpret_cast<const f32x4*>(wp + 4);
    half8 hv;
    #pragma unroll
    for (int j = 0; j < 4; ++j) { hv[j] = (_Float16)w0[j]; hv[4+j] = (_Float16)w1[j]; }
    *reinterpret_cast<half8*>(&Bs[u*8]) = hv;
  }
  __syncthreads();

  const int wave = t >> 6, lane = t & 63;
  const int lr = lane & 15, lq = lane >> 4;
  const int rowBase = m0 + wave*64;
  const int kBase = lq*8;

  const TA* aptr[4];
  #pragma unroll
  for (int r = 0; r < 4; ++r) {
    int gm = rowBase + r*16 + lr;
    if (gm > M-1) gm = M-1;
    aptr[r] = A + (size_t)gm*lda + coff + kBase;
  }

  f32x4 acc[4][4] = {};
  #pragma unroll
  for (int k0 = 0; k0 < KT; k0 += 32) {
    half8 b[4];
    #pragma unroll
    for (int c = 0; c < 4; ++c)
      b[c] = *reinterpret_cast<const half8*>(&Bs[(((k0>>5)<<2) + c)*512 + lane*8]);
    half8 a[4];
    #pragma unroll
    for (int r = 0; r < 4; ++r) {
      const TA* ap = aptr[r] + k0;
      if constexpr (std::is_same<TA, float>::value) {
        f32x4 u0 = *reinterpret_cast<const f32x4*>(ap);
        f32x4 u1 = *reinterpret_cast<const f32x4*>(ap + 4);
        half8 av;
        #pragma unroll
        for (int j = 0; j < 4; ++j) { av[j] = (_Float16)u0[j]; av[4+j] = (_Float16)u1[j]; }
        a[r] = av;
      } else {
        a[r] = *reinterpret_cast<const half8*>(ap);
      }
    }
    #pragma unroll
    for (int r = 0; r < 4; ++r)
      #pragma unroll
      for (int c = 0; c < 4; ++c)
        acc[r][c] = __builtin_amdgcn_mfma_f32_16x16x32_f16(a[r], b[c], acc[r][c], 0, 0, 0);
  }

  float bvv[4];
  #pragma unroll
  for (int c = 0; c < 4; ++c)
    bvv[c] = bias ? bias[n0 + c*16 + lr] : 0.f;
  #pragma unroll
  for (int r = 0; r < 4; ++r) {
    #pragma unroll
    for (int j = 0; j < 4; ++j) {
      int gm = rowBase + r*16 + lq*4 + j;
      if (gm >= M) continue;
      float Cf = 1.f;
      if (CUT) {
        float wv = cw[gm];
        Cf = (wv < 5.f) ? 0.5f*(__cosf(wv*0.62831853071795864769f) + 1.f) : 0.f;
      }
      _Float16* crow = C + (size_t)gm*ldc + coff + n0;
      #pragma unroll
      for (int c = 0; c < 4; ++c) {
        float v = acc[r][c][j] + bvv[c];
        if (ACT) v = v / (1.f + __expf(-v));
        if (CUT) v *= Cf;
        crow[c*16 + lr] = (_Float16)v;
      }
    }
  }
}

// ---------------------------------------------------------------------------
// CSR build over src
// ---------------------------------------------------------------------------
__global__ void k_zero_i(int* __restrict__ p, int n) {
  int i = blockIdx.x*256 + threadIdx.x;
  if (i < n) p[i] = 0;
}
__global__ void k_hist(const int* __restrict__ src, int* __restrict__ cnt) {
  int e = blockIdx.x*256 + threadIdx.x;
  if (e < EE) atomicAdd(&cnt[src[e]], 1);
}
__global__ __launch_bounds__(1024) void k_scan(const int* __restrict__ cnt,
                                               int* __restrict__ off,
                                               int* __restrict__ cur) {
  __shared__ int s[1024];
  __shared__ int carry;
  int t = threadIdx.x;
  if (t == 0) carry = 0;
  __syncthreads();
  for (int base = 0; base < NN; base += 1024) {
    int i = base + t;
    int v = (i < NN) ? cnt[i] : 0;
    s[t] = v; __syncthreads();
    for (int d = 1; d < 1024; d <<= 1) {
      int x = (t >= d) ? s[t-d] : 0; __syncthreads();
      s[t] += x; __syncthreads();
    }
    int incl = s[t];
    int total = s[1023];
    int excl = incl - v + carry;
    if (i < NN) { off[i] = excl; cur[i] = excl; }
    __syncthreads();
    if (t == 0) carry += total;
    __syncthreads();
  }
  if (t == 0) off[NN] = carry;
}
__global__ void k_scatter(const int* __restrict__ src, int* __restrict__ cur,
                          int* __restrict__ elist) {
  int e = blockIdx.x*256 + threadIdx.x;
  if (e < EE) { int pos = atomicAdd(&cur[src[e]], 1); elist[pos] = e; }
}

// ---------------------------------------------------------------------------
// Message passing: one block per node; decomposed accumulation (I:1,A:3,S:6).
// ea already includes the cutoff factor.
// ---------------------------------------------------------------------------
__global__ __launch_bounds__(256) void k_message(
    const __half* __restrict__ ea, const __half* __restrict__ T1,
    const int* __restrict__ dstArr,
    const int* __restrict__ off, const int* __restrict__ elist,
    __half* __restrict__ msg)
{
  int n = blockIdx.x;
  int t = threadIdx.x;
  int o = t & 127, ph = t >> 7;
  int e0 = off[n], e1 = off[n+1];
  float acc0=0.f, acc1=0.f, acc2=0.f, acc3=0.f, acc4=0.f;
  for (int ii = e0; ii < e1; ++ii) {
    int e = elist[ii];
    int d = dstArr[e];
    const __half* he = &ea[(size_t)e*384 + 3*o];
    const __half* Td = &T1[(size_t)d*1280 + o];
    if (ph == 0) {
      float f0 = (float)he[0];
      float f1 = (float)he[1];
      float f2 = (float)he[2];
      acc0 += f0 * (float)Td[0];      // lam'
      acc1 += f1 * (float)Td[128];    // a0'
      acc2 += f1 * (float)Td[256];    // a1'
      acc3 += f1 * (float)Td[384];    // a2'
      acc4 += f2 * (float)Td[512];    // s00'
    } else {
      float f2 = (float)he[2];
      acc0 += f2 * (float)Td[640];    // s01'
      acc1 += f2 * (float)Td[768];    // s02'
      acc2 += f2 * (float)Td[896];    // s11'
      acc3 += f2 * (float)Td[1024];   // s12'
      acc4 += f2 * (float)Td[1152];   // s22'
    }
  }
  __half* mn = &msg[(size_t)n*1280 + o];
  int pb = ph * 5;
  mn[(pb+0)*128] = __float2half(acc0);
  mn[(pb+1)*128] = __float2half(acc1);
  mn[(pb+2)*128] = __float2half(acc2);
  mn[(pb+3)*128] = __float2half(acc3);
  mn[(pb+4)*128] = __float2half(acc4);
}

// ---------------------------------------------------------------------------
// Bracket: B = M*Y + Y*M ; decompose ; /(tnorm(B)+1) -> D2
// D2 may alias T1 (in-place): no __restrict__ on those params.
// ---------------------------------------------------------------------------
__global__ __launch_bounds__(256) void k_bracket(
    const __half* __restrict__ msgp, const __half* T1, __half* D2)
{
  int idx = blockIdx.x*256 + threadIdx.x;
  int n = idx >> 7, o = idx & 127;
  const __half* Mc = &msgp[(size_t)n*1280 + o];
  const __half* Yc = &T1[(size_t)n*1280 + o];
  float Mm[9], Ym[9];
  {
    float lam=(float)Mc[0], a0=(float)Mc[128], a1=(float)Mc[256], a2=(float)Mc[384];
    float s00=(float)Mc[512], s01=(float)Mc[640], s02=(float)Mc[768];
    float s11=(float)Mc[896], s12=(float)Mc[1024], s22=(float)Mc[1152];
    Mm[0]=lam+s00; Mm[1]=a0+s01;  Mm[2]=a1+s02;
    Mm[3]=s01-a0;  Mm[4]=lam+s11; Mm[5]=a2+s12;
    Mm[6]=s02-a1;  Mm[7]=s12-a2;  Mm[8]=lam+s22;
  }
  {
    float lam=(float)Yc[0], a0=(float)Yc[128], a1=(float)Yc[256], a2=(float)Yc[384];
    float s00=(float)Yc[512], s01=(float)Yc[640], s02=(float)Yc[768];
    float s11=(float)Yc[896], s12=(float)Yc[1024], s22=(float)Yc[1152];
    Ym[0]=lam+s00; Ym[1]=a0+s01;  Ym[2]=a1+s02;
    Ym[3]=s01-a0;  Ym[4]=lam+s11; Ym[5]=a2+s12;
    Ym[6]=s02-a1;  Ym[7]=s12-a2;  Ym[8]=lam+s22;
  }
  float B[9];
  #pragma unroll
  for (int i = 0; i < 3; ++i) {
    #pragma unroll
    for (int j = 0; j < 3; ++j) {
      float s = 0.f;
      #pragma unroll
      for (int k = 0; k < 3; ++k)
        s += Mm[i*3+k]*Ym[k*3+j] + Ym[i*3+k]*Mm[k*3+j];
      B[i*3+j] = s;
    }
  }
  float lamb = (B[0]+B[4]+B[8]) * (1.f/3.f);
  float ss = 0.f;
  #pragma unroll
  for (int qq = 0; qq < 9; ++qq) ss += B[qq]*B[qq];
  float inv = 1.f / (fmaxf(ss, 0.01f) + 1.f);
  __half* Dn = &D2[(size_t)n*1280 + o];
  Dn[0]    = __float2half(lamb*inv);
  Dn[128]  = __float2half(0.5f*(B[1]-B[3])*inv);
  Dn[256]  = __float2half(0.5f*(B[2]-B[6])*inv);
  Dn[384]  = __float2half(0.5f*(B[5]-B[7])*inv);
  Dn[512]  = __float2half((B[0]-lamb)*inv);
  Dn[640]  = __float2half(0.5f*(B[1]+B[3])*inv);
  Dn[768]  = __float2half(0.5f*(B[2]+B[6])*inv);
  Dn[896]  = __float2half((B[4]-lamb)*inv);
  Dn[1024] = __float2half(0.5f*(B[5]+B[7])*inv);
  Dn[1152] = __float2half((B[8]-lamb)*inv);
}

// ---------------------------------------------------------------------------
// Final: out = Xn + reconstruct(Tb)
// ---------------------------------------------------------------------------
__global__ __launch_bounds__(256) void k_final(
    const __half* __restrict__ Xn, const __half* __restrict__ Tb,
    float* __restrict__ out)
{
  int idx = blockIdx.x*256 + threadIdx.x;
  int n = idx >> 7, o = idx & 127;
  const __half* Tc = &Tb[(size_t)n*1280 + o];
  float lam=(float)Tc[0], a0=(float)Tc[128], a1=(float)Tc[256], a2=(float)Tc[384];
  float s00=(float)Tc[512], s01=(float)Tc[640], s02=(float)Tc[768];
  float s11=(float)Tc[896], s12=(float)Tc[1024], s22=(float)Tc[1152];
  const __half* xc = &Xn[(size_t)n*1152 + o*9];
  float* oc = &out[(size_t)n*1152 + o*9];
  oc[0] = (float)xc[0] + lam + s00;
  oc[1] = (float)xc[1] + a0  + s01;
  oc[2] = (float)xc[2] + a1  + s02;
  oc[3] = (float)xc[3] - a0  + s01;
  oc[4] = (float)xc[4] + lam + s11;
  oc[5] = (float)xc[5] + a2  + s12;
  oc[6] = (float)xc[6] - a1  + s02;
  oc[7] = (float)xc[7] - a2  + s12;
  oc[8] = (float)xc[8] + lam + s22;
}

// ---------------------------------------------------------------------------
extern "C" void kernel_launch(void* const* d_in, const int* in_sizes, int n_in,
                              void* d_out, int out_size, void* d_ws, size_t ws_size,
                              hipStream_t stream)
{
  const float* X     = (const float*)d_in[0];
  const float* ew    = (const float*)d_in[1];
  const float* eattr = (const float*)d_in[2];
  const float* Wp    = (const float*)d_in[3];
  const float* bp    = (const float*)d_in[4];
  const float* Ws0   = (const float*)d_in[5];
  const float* bs0   = (const float*)d_in[6];
  const float* Ws1   = (const float*)d_in[7];
  const float* bs1   = (const float*)d_in[8];
  const float* Ws2   = (const float*)d_in[9];
  const float* bs2   = (const float*)d_in[10];
  const int*   eidx  = (const int*)d_in[11];
  const float* Wt0   = (const float*)d_in[12];
  const float* Wt1   = (const float*)d_in[13];
  const float* Wt2   = (const float*)d_in[14];
  const float* Wt3   = (const float*)d_in[15];
  const float* Wt4   = (const float*)d_in[16];
  const float* Wt5   = (const float*)d_in[17];
  float* out = (float*)d_out;

  // Packed lifetime-aliased layout, peak 254,424,064 B:
  //  A [0,          23,040,000)  Xn fp16                  [node_post -> final]
  //  B [23,040,000, 48,640,000)  T1 fp16 -> D2 (in-place) [K2 -> K4]
  //  C [48,640,000, 130,560,000) {D1 | Xt | Xp} -> h1 -> msg -> Tb
  //  D [130,560,000,253,440,000) h0 -> ea                 (122.88 MB)
  //  csr [253,440,000, 254,161,920)
  //  Wfl [254,161,920, 254,424,064)  frag-linear fp16 Ws1, Ws2
  const size_t NEED = 254424064;
  if (ws_size < NEED) return;   // diagnostic: poison-fail instead of fault

  char* base = (char*)d_ws;
  __half*   Xn  = (__half*)(base);
  __half*   T1  = (__half*)(base + 23040000);
  __half*   D1  = (__half*)(base + 48640000);          // 25.6 MB [node_post -> K2]
  _Float16* Xt  = (_Float16*)(base + 74240000);        // 23.04 MB [pre -> gemm]
  _Float16* Xp  = (_Float16*)(base + 97280000);        // 23.04 MB [gemm -> post]
  __half*   h1  = (__half*)(base + 48640000);
  __half*   msg = (__half*)(base + 48640000);
  __half*   Tb  = (__half*)(base + 48640000);
  __half*   h0  = (__half*)(base + 130560000);
  __half*   ea  = (__half*)(base + 130560000);
  char*     csr = base + 253440000;
  int* off_  = (int*)csr;
  int* cur_  = (int*)(csr + 40960);
  int* elist = (int*)(csr + 81920);
  _Float16* W1fl = (_Float16*)(base + 254161920);      // 65,536 B
  _Float16* W2fl = (_Float16*)(base + 254227456);      // 196,608 B

  (void)in_sizes; (void)n_in; (void)out_size;

  // weight pre-pack (frag-linear fp16) for the pipelined GEMMs
  k_wprep<<<16, 256, 0, stream>>>(Ws1, W1fl, 256, 128);
  k_wprep<<<48, 256, 0, stream>>>(Ws2, W2fl, 384, 256);

  // node phase: pack -> MFMA GEMM (M=90000,K=128,N=128, bias=bp) -> norm/decompose
  k_node_pre<<<2500, 256, 0, stream>>>(X, Xt);
  k_gemm_mfma<_Float16, 128, false, false, false><<<dim3(352*2, 1, 1), 256, 0, stream>>>(
      Xt, 128, Wp, nullptr, nullptr, bp, nullptr, Xp, 128, 9*NN, 2);
  k_node_post<<<5000, 256, 0, stream>>>(Xp, Xn, D1);

  // T' = clin(I,Wt0)/clin(A,Wt1)/clin(S,Wt2): 10 slices of [10000 x 128 x 128]
  k_gemm_mfma<_Float16, 128, false, false, true><<<dim3(40*2, 1, 10), 256, 0, stream>>>(
      (_Float16*)D1, 1280, Wt0, Wt1, Wt2, nullptr, nullptr, (_Float16*)T1, 1280, NN, 2);

  // edge MLP: layer1 (old kernel, f32 A), layers 2-3 pipelined
  k_gemm_mfma<float, 32, true, false, false><<<dim3(625*2, 1, 1), 256, 0, stream>>>(
      eattr, 32, Ws0, nullptr, nullptr, bs0, nullptr, (_Float16*)h0, 128, EE, 2);
  k_gemm_pipe<128, true, false><<<2500, 256, 0, stream>>>(
      (_Float16*)h0, W1fl, bs1, nullptr, (_Float16*)h1, 256, EE, 2);
  k_gemm_pipe<256, true, true><<<3750, 256, 0, stream>>>(
      (_Float16*)h1, W2fl, bs2, ew, (_Float16*)ea, 384, EE, 3);

  // CSR over src
  k_zero_i<<<40, 256, 0, stream>>>(cur_, NN);
  k_hist<<<625, 256, 0, stream>>>(eidx, cur_);
  k_scan<<<1, 1024, 0, stream>>>(cur_, off_, cur_);
  k_scatter<<<625, 256, 0, stream>>>(eidx, cur_, elist);

  // message passing (gather T'[dst], reduce per src node)
  k_message<<<NN, 256, 0, stream>>>(ea, T1, eidx + EE, off_, elist, msg);

  // bracket + decompose + norm (D2 overwrites T1 in-place)
  k_bracket<<<5000, 256, 0, stream>>>(msg, T1, T1);

  // dX components = clin with Wt3/4/5
  k_gemm_mfma<_Float16, 128, false, false, true><<<dim3(40*2, 1, 10), 256, 0, stream>>>(
      (_Float16*)T1, 1280, Wt3, Wt4, Wt5, nullptr, nullptr, (_Float16*)Tb, 1280, NN, 2);

  // out = Xn + reconstruct(dX)
  k_final<<<5000, 256, 0, stream>>>(Xn, Tb, out);
}

// Round 7
// 382.082 us; speedup vs baseline: 1.2069x; 1.0659x over previous
//
#include <hip/hip_runtime.h>
#include <hip/hip_fp16.h>
#include <type_traits>

#define NN 10000
#define EE 160000

typedef _Float16 half8 __attribute__((ext_vector_type(8)));
typedef float    f32x4 __attribute__((ext_vector_type(4)));

// ---------------------------------------------------------------------------
// Node phase:
//  pre : Xt[(n,ij)][c] fp16  <- X[n][c][ij] f32      (pack/transpose)
//  gemm: Xp[(n,ij)][o] = sum_c Xt * Wp[o][c] + bp[o] (k_gemm_pipe)
//  post: per (n,o): norm over 9 ij, decompose -> Xn[n][o][ij], D1[n][10][128]
// ---------------------------------------------------------------------------
__global__ __launch_bounds__(256) void k_node_pre(
    const float* __restrict__ X, _Float16* __restrict__ Xt)
{
  __shared__ float Xl[4*1152];
  const int n0 = blockIdx.x * 4;
  const int t = threadIdx.x;
  const float* src = X + (size_t)n0*1152;
  #pragma unroll
  for (int idx = t; idx < 4*1152; idx += 256) Xl[idx] = src[idx];
  __syncthreads();
  _Float16* dst = Xt + (size_t)n0*1152;
  #pragma unroll
  for (int idx = t; idx < 4*1152; idx += 256) {
    int node = idx / 1152, rem = idx - node*1152;
    int ij = rem >> 7, c = rem & 127;
    dst[idx] = (_Float16)Xl[node*1152 + c*9 + ij];   // stride-9 LDS: odd -> conflict-free
  }
}

__global__ __launch_bounds__(256) void k_node_post(
    const _Float16* __restrict__ Xp,
    __half* __restrict__ Xn, __half* __restrict__ D1)
{
  int idx = blockIdx.x*256 + threadIdx.x;
  int n = idx >> 7, o = idx & 127;
  float m[9], ss = 0.f;
  #pragma unroll
  for (int ij = 0; ij < 9; ++ij) {
    m[ij] = (float)Xp[((size_t)n*9 + ij)*128 + o];   // coalesced across o
    ss += m[ij]*m[ij];
  }
  ss = fmaxf(ss, 0.01f);
  float inv = 1.f / (ss + 1.f);
  #pragma unroll
  for (int ij = 0; ij < 9; ++ij) m[ij] *= inv;
  __half* xo = &Xn[(size_t)n*1152 + o*9];
  #pragma unroll
  for (int ij = 0; ij < 9; ++ij) xo[ij] = __float2half(m[ij]);
  float lam = (m[0]+m[4]+m[8]) * (1.f/3.f);
  __half* Dn = &D1[(size_t)n*1280];
  Dn[0*128+o] = __float2half(lam);
  Dn[1*128+o] = __float2half(0.5f*(m[1]-m[3]));
  Dn[2*128+o] = __float2half(0.5f*(m[2]-m[6]));
  Dn[3*128+o] = __float2half(0.5f*(m[5]-m[7]));
  Dn[4*128+o] = __float2half(m[0]-lam);
  Dn[5*128+o] = __float2half(0.5f*(m[1]+m[3]));
  Dn[6*128+o] = __float2half(0.5f*(m[2]+m[6]));
  Dn[7*128+o] = __float2half(m[4]-lam);
  Dn[8*128+o] = __float2half(0.5f*(m[5]+m[7]));
  Dn[9*128+o] = __float2half(m[8]-lam);
}

// ---------------------------------------------------------------------------
// Weight pre-pack: W [N][K] f32 -> fragment-linear fp16
//   Wfl[((kc*(N/16) + nf)*64 + lane)*8 + j] = W[nf*16 + (lane&15)][kc*32 + (lane>>4)*8 + j]
// ---------------------------------------------------------------------------
__global__ __launch_bounds__(256) void k_wprep(
    const float* __restrict__ W, _Float16* __restrict__ Wfl, int N, int K)
{
  int u = blockIdx.x*256 + threadIdx.x;
  int total = (N >> 4) * (K >> 5) * 64;
  if (u >= total) return;
  int lane = u & 63, rest = u >> 6;
  int nfTotal = N >> 4;
  int nf = rest % nfTotal, kc = rest / nfTotal;
  int n = nf*16 + (lane & 15);
  int k = kc*32 + (lane >> 4)*8;
  const float* src = W + (size_t)n*K + k;
  half8 hv;
  #pragma unroll
  for (int j = 0; j < 8; ++j) hv[j] = (_Float16)src[j];
  *reinterpret_cast<half8*>(Wfl + (size_t)u*8) = hv;
}

// ---------------------------------------------------------------------------
// Pipelined MFMA GEMM (m97 structure): C[m][n] = post(sum_k A[m][k]*W[n][k]+b[n])
//   - BM=128, BN=128, BK=32, 4 waves; wave owns 32 rows x 128 cols (acc[2][8])
//   - A and W double-buffered via global_load_lds width-16 DMA
//   - A LDS seg pre-swizzled seg^(row&3) at source; read seg = lq^(lr&3)
//   - rowmap (optional): output row permutation (CSR-ordered ea write)
//   - requires lda == KT; M clamped per-row
// ---------------------------------------------------------------------------
template<int KT, bool ACT, bool CUT>
__global__ __launch_bounds__(256, 4) void k_gemm_pipe(
    const _Float16* __restrict__ A,
    const _Float16* __restrict__ Wfl,
    const float* __restrict__ bias, const float* __restrict__ cw,
    const int* __restrict__ rowmap,
    _Float16* __restrict__ C, int ldc,
    int M, int nTiles)
{
  constexpr int NC = KT / 32;
  __shared__ _Float16 Abuf[2][128*32];
  __shared__ _Float16 Wbuf[2][128*32];
  const int t = threadIdx.x;
  const int nfTotal = nTiles * 8;

  // XCD-bijective block swizzle (m204), n-tile fastest
  int nwg = gridDim.x, bid = blockIdx.x;
  int q = nwg >> 3, rr = nwg & 7;
  int xcd = bid & 7, ii = bid >> 3;
  int swz = (xcd < rr) ? xcd*(q+1) + ii : rr*(q+1) + (xcd-rr)*q + ii;
  int nt = swz % nTiles, mt = swz / nTiles;
  const int n0 = nt * 128, m0 = mt * 128;

  auto stage = [&](int d, int kc) {
    #pragma unroll
    for (int i = 0; i < 2; ++i) {
      int u = t + i*256;
      int row = u >> 2, seg = u & 3;
      int gm = m0 + row; if (gm > M-1) gm = M-1;
      const _Float16* gp = A + (size_t)gm*KT + kc*32 + ((seg ^ (row & 3)) << 3);
      __builtin_amdgcn_global_load_lds(
          (const __attribute__((address_space(1))) _Float16*)gp,
          (__attribute__((address_space(3))) _Float16*)(&Abuf[d][u*8]), 16, 0, 0);
    }
    const _Float16* wp = Wfl + (((size_t)kc*nfTotal + nt*8) << 9);
    #pragma unroll
    for (int i = 0; i < 2; ++i) {
      int u = t + i*256;
      __builtin_amdgcn_global_load_lds(
          (const __attribute__((address_space(1))) _Float16*)(wp + u*8),
          (__attribute__((address_space(3))) _Float16*)(&Wbuf[d][u*8]), 16, 0, 0);
    }
  };

  const int wave = t >> 6, lane = t & 63;
  const int lr = lane & 15, lq = lane >> 4;
  const int wrow = wave * 32;
  const int aoff = (lq ^ (lr & 3)) << 3;

  f32x4 acc[2][8] = {};

  stage(0, 0);
  __syncthreads();
  int cur = 0;
  for (int kc = 0; kc < NC; ++kc) {
    if (kc + 1 < NC) stage(cur ^ 1, kc + 1);
    const _Float16* ab = &Abuf[cur][0];
    const _Float16* wb = &Wbuf[cur][0];
    half8 a0 = *reinterpret_cast<const half8*>(ab + (wrow + lr)*32 + aoff);
    half8 a1 = *reinterpret_cast<const half8*>(ab + (wrow + 16 + lr)*32 + aoff);
    #pragma unroll
    for (int c = 0; c < 8; ++c) {
      half8 b = *reinterpret_cast<const half8*>(wb + c*512 + lane*8);
      acc[0][c] = __builtin_amdgcn_mfma_f32_16x16x32_f16(a0, b, acc[0][c], 0, 0, 0);
      acc[1][c] = __builtin_amdgcn_mfma_f32_16x16x32_f16(a1, b, acc[1][c], 0, 0, 0);
    }
    if (kc + 1 < NC) { __syncthreads(); cur ^= 1; }
  }

  // epilogue
  float bvv[8];
  #pragma unroll
  for (int c = 0; c < 8; ++c) bvv[c] = bias[n0 + c*16 + lr];
  #pragma unroll
  for (int r = 0; r < 2; ++r) {
    #pragma unroll
    for (int j = 0; j < 4; ++j) {
      int gm = m0 + wrow + r*16 + lq*4 + j;   // C/D: col=lane&15, row=(lane>>4)*4+reg
      if (gm >= M) continue;
      float Cf = 1.f;
      if (CUT) {
        float wv = cw[gm];
        Cf = (wv < 5.f) ? 0.5f*(__cosf(wv*0.62831853071795864769f) + 1.f) : 0.f;
      }
      int orow = rowmap ? rowmap[gm] : gm;
      _Float16* crow = C + (size_t)orow*ldc + n0;
      #pragma unroll
      for (int c = 0; c < 8; ++c) {
        float v = acc[r][c][j] + bvv[c];
        if (ACT) v = v / (1.f + __expf(-v));   // silu
        if (CUT) v *= Cf;
        crow[c*16 + lr] = (_Float16)v;
      }
    }
  }
}

// ---------------------------------------------------------------------------
// MFMA GEMM (non-pipelined; small/odd-shaped GEMMs):
//   BM=256, BN=64; W staged fp32->fp16 fragment-linear LDS (conflict-free)
//   PSEL: blockIdx.z = p in 0..9: W = p==0?W0 : p<4?W1 : W2; A,C col-offset p*128
// ---------------------------------------------------------------------------
template<typename TA, int KT, bool ACT, bool CUT, bool PSEL>
__global__ __launch_bounds__(256) void k_gemm_mfma(
    const TA* __restrict__ A, int lda,
    const float* __restrict__ W0, const float* __restrict__ W1, const float* __restrict__ W2,
    const float* __restrict__ bias, const float* __restrict__ cw,
    _Float16* __restrict__ C, int ldc,
    int M, int nTiles)
{
  constexpr int NFRAG = (KT/32)*4;
  __shared__ _Float16 Bs[NFRAG*64*8];
  const int t = threadIdx.x;

  int nwg = gridDim.x;
  int bid = blockIdx.x;
  int q = nwg >> 3, rr = nwg & 7;
  int xcd = bid & 7, ii = bid >> 3;
  int swz = (xcd < rr) ? xcd*(q+1) + ii : rr*(q+1) + (xcd-rr)*q + ii;
  int nt = swz % nTiles;
  int mt = swz / nTiles;

  const float* W = W0;
  int coff = 0;
  if (PSEL) {
    int p = blockIdx.z;
    W = (p == 0) ? W0 : (p < 4 ? W1 : W2);
    coff = p * 128;
  }
  const int n0 = nt * 64;
  const int m0 = mt * 256;

  #pragma unroll
  for (int u = t; u < NFRAG*64; u += 256) {
    int g = u >> 6, lu = u & 63;
    int lru = lu & 15, lqu = lu >> 4;
    int nn = (g & 3)*16 + lru;
    int kk = (g >> 2)*32 + lqu*8;
    const float* wp = &W[(size_t)(n0 + nn)*KT + kk];
    f32x4 w0 = *reinterpret_cast<const f32x4*>(wp);
    f32x4 w1 = *reinterpret_cast<const f32x4*>(wp + 4);
    half8 hv;
    #pragma unroll
    for (int j = 0; j < 4; ++j) { hv[j] = (_Float16)w0[j]; hv[4+j] = (_Float16)w1[j]; }
    *reinterpret_cast<half8*>(&Bs[u*8]) = hv;
  }
  __syncthreads();

  const int wave = t >> 6, lane = t & 63;
  const int lr = lane & 15, lq = lane >> 4;
  const int rowBase = m0 + wave*64;
  const int kBase = lq*8;

  const TA* aptr[4];
  #pragma unroll
  for (int r = 0; r < 4; ++r) {
    int gm = rowBase + r*16 + lr;
    if (gm > M-1) gm = M-1;
    aptr[r] = A + (size_t)gm*lda + coff + kBase;
  }

  f32x4 acc[4][4] = {};
  #pragma unroll
  for (int k0 = 0; k0 < KT; k0 += 32) {
    half8 b[4];
    #pragma unroll
    for (int c = 0; c < 4; ++c)
      b[c] = *reinterpret_cast<const half8*>(&Bs[(((k0>>5)<<2) + c)*512 + lane*8]);
    half8 a[4];
    #pragma unroll
    for (int r = 0; r < 4; ++r) {
      const TA* ap = aptr[r] + k0;
      if constexpr (std::is_same<TA, float>::value) {
        f32x4 u0 = *reinterpret_cast<const f32x4*>(ap);
        f32x4 u1 = *reinterpret_cast<const f32x4*>(ap + 4);
        half8 av;
        #pragma unroll
        for (int j = 0; j < 4; ++j) { av[j] = (_Float16)u0[j]; av[4+j] = (_Float16)u1[j]; }
        a[r] = av;
      } else {
        a[r] = *reinterpret_cast<const half8*>(ap);
      }
    }
    #pragma unroll
    for (int r = 0; r < 4; ++r)
      #pragma unroll
      for (int c = 0; c < 4; ++c)
        acc[r][c] = __builtin_amdgcn_mfma_f32_16x16x32_f16(a[r], b[c], acc[r][c], 0, 0, 0);
  }

  float bvv[4];
  #pragma unroll
  for (int c = 0; c < 4; ++c)
    bvv[c] = bias ? bias[n0 + c*16 + lr] : 0.f;
  #pragma unroll
  for (int r = 0; r < 4; ++r) {
    #pragma unroll
    for (int j = 0; j < 4; ++j) {
      int gm = rowBase + r*16 + lq*4 + j;
      if (gm >= M) continue;
      float Cf = 1.f;
      if (CUT) {
        float wv = cw[gm];
        Cf = (wv < 5.f) ? 0.5f*(__cosf(wv*0.62831853071795864769f) + 1.f) : 0.f;
      }
      _Float16* crow = C + (size_t)gm*ldc + coff + n0;
      #pragma unroll
      for (int c = 0; c < 4; ++c) {
        float v = acc[r][c][j] + bvv[c];
        if (ACT) v = v / (1.f + __expf(-v));
        if (CUT) v *= Cf;
        crow[c*16 + lr] = (_Float16)v;
      }
    }
  }
}

// ---------------------------------------------------------------------------
// CSR build over src. Scatter also emits inv[e]=pos and dst_s[pos]=dst[e]
// so G3 can write ea in CSR order and k_message streams it sequentially.
// ---------------------------------------------------------------------------
__global__ void k_zero_i(int* __restrict__ p, int n) {
  int i = blockIdx.x*256 + threadIdx.x;
  if (i < n) p[i] = 0;
}
__global__ void k_hist(const int* __restrict__ src, int* __restrict__ cnt) {
  int e = blockIdx.x*256 + threadIdx.x;
  if (e < EE) atomicAdd(&cnt[src[e]], 1);
}
__global__ __launch_bounds__(1024) void k_scan(const int* __restrict__ cnt,
                                               int* __restrict__ off,
                                               int* __restrict__ cur) {
  __shared__ int s[1024];
  __shared__ int carry;
  int t = threadIdx.x;
  if (t == 0) carry = 0;
  __syncthreads();
  for (int base = 0; base < NN; base += 1024) {
    int i = base + t;
    int v = (i < NN) ? cnt[i] : 0;
    s[t] = v; __syncthreads();
    for (int d = 1; d < 1024; d <<= 1) {
      int x = (t >= d) ? s[t-d] : 0; __syncthreads();
      s[t] += x; __syncthreads();
    }
    int incl = s[t];
    int total = s[1023];
    int excl = incl - v + carry;
    if (i < NN) { off[i] = excl; cur[i] = excl; }
    __syncthreads();
    if (t == 0) carry += total;
    __syncthreads();
  }
  if (t == 0) off[NN] = carry;
}
__global__ void k_scatter(const int* __restrict__ src, const int* __restrict__ dst,
                          int* __restrict__ cur,
                          int* __restrict__ inv, int* __restrict__ dst_s) {
  int e = blockIdx.x*256 + threadIdx.x;
  if (e < EE) {
    int pos = atomicAdd(&cur[src[e]], 1);
    inv[e] = pos;
    dst_s[pos] = dst[e];
  }
}

// ---------------------------------------------------------------------------
// Message passing: ea_s is CSR-ordered -> block reads its rows SEQUENTIALLY.
// 2 nodes/block, 128 lanes/node; each lane handles one o and all 10 comps
// (single pass over each ea row: no multi-wave drift re-fetch).
// ---------------------------------------------------------------------------
__global__ __launch_bounds__(256) void k_message(
    const __half* __restrict__ ea_s, const __half* __restrict__ T1,
    const int* __restrict__ dst_s, const int* __restrict__ off,
    __half* __restrict__ msg)
{
  const int t = threadIdx.x;
  const int o = t & 127;
  const int n = blockIdx.x*2 + (t >> 7);
  const int e0 = off[n], e1 = off[n+1];
  float acc[10] = {};
  auto edge = [&](int ii) {
    const __half* he = ea_s + (size_t)ii*384 + 3*o;
    float f0 = (float)he[0], f1 = (float)he[1], f2 = (float)he[2];
    int d = dst_s[ii];
    const __half* Td = T1 + (size_t)d*1280 + o;
    acc[0] += f0 * (float)Td[0];
    acc[1] += f1 * (float)Td[128];
    acc[2] += f1 * (float)Td[256];
    acc[3] += f1 * (float)Td[384];
    #pragma unroll
    for (int c = 4; c < 10; ++c) acc[c] += f2 * (float)Td[c*128];
  };
  int ii = e0;
  for (; ii + 2 <= e1; ii += 2) { edge(ii); edge(ii+1); }
  if (ii < e1) edge(ii);
  __half* mn = &msg[(size_t)n*1280 + o];
  #pragma unroll
  for (int c = 0; c < 10; ++c) mn[c*128] = __float2half(acc[c]);
}

// ---------------------------------------------------------------------------
// Bracket: B = M*Y + Y*M ; decompose ; /(tnorm(B)+1) -> D2
// D2 may alias T1 (in-place): no __restrict__ on those params.
// ---------------------------------------------------------------------------
__global__ __launch_bounds__(256) void k_bracket(
    const __half* __restrict__ msgp, const __half* T1, __half* D2)
{
  int idx = blockIdx.x*256 + threadIdx.x;
  int n = idx >> 7, o = idx & 127;
  const __half* Mc = &msgp[(size_t)n*1280 + o];
  const __half* Yc = &T1[(size_t)n*1280 + o];
  float Mm[9], Ym[9];
  {
    float lam=(float)Mc[0], a0=(float)Mc[128], a1=(float)Mc[256], a2=(float)Mc[384];
    float s00=(float)Mc[512], s01=(float)Mc[640], s02=(float)Mc[768];
    float s11=(float)Mc[896], s12=(float)Mc[1024], s22=(float)Mc[1152];
    Mm[0]=lam+s00; Mm[1]=a0+s01;  Mm[2]=a1+s02;
    Mm[3]=s01-a0;  Mm[4]=lam+s11; Mm[5]=a2+s12;
    Mm[6]=s02-a1;  Mm[7]=s12-a2;  Mm[8]=lam+s22;
  }
  {
    float lam=(float)Yc[0], a0=(float)Yc[128], a1=(float)Yc[256], a2=(float)Yc[384];
    float s00=(float)Yc[512], s01=(float)Yc[640], s02=(float)Yc[768];
    float s11=(float)Yc[896], s12=(float)Yc[1024], s22=(float)Yc[1152];
    Ym[0]=lam+s00; Ym[1]=a0+s01;  Ym[2]=a1+s02;
    Ym[3]=s01-a0;  Ym[4]=lam+s11; Ym[5]=a2+s12;
    Ym[6]=s02-a1;  Ym[7]=s12-a2;  Ym[8]=lam+s22;
  }
  float B[9];
  #pragma unroll
  for (int i = 0; i < 3; ++i) {
    #pragma unroll
    for (int j = 0; j < 3; ++j) {
      float s = 0.f;
      #pragma unroll
      for (int k = 0; k < 3; ++k)
        s += Mm[i*3+k]*Ym[k*3+j] + Ym[i*3+k]*Mm[k*3+j];
      B[i*3+j] = s;
    }
  }
  float lamb = (B[0]+B[4]+B[8]) * (1.f/3.f);
  float ss = 0.f;
  #pragma unroll
  for (int qq = 0; qq < 9; ++qq) ss += B[qq]*B[qq];
  float inv = 1.f / (fmaxf(ss, 0.01f) + 1.f);
  __half* Dn = &D2[(size_t)n*1280 + o];
  Dn[0]    = __float2half(lamb*inv);
  Dn[128]  = __float2half(0.5f*(B[1]-B[3])*inv);
  Dn[256]  = __float2half(0.5f*(B[2]-B[6])*inv);
  Dn[384]  = __float2half(0.5f*(B[5]-B[7])*inv);
  Dn[512]  = __float2half((B[0]-lamb)*inv);
  Dn[640]  = __float2half(0.5f*(B[1]+B[3])*inv);
  Dn[768]  = __float2half(0.5f*(B[2]+B[6])*inv);
  Dn[896]  = __float2half((B[4]-lamb)*inv);
  Dn[1024] = __float2half(0.5f*(B[5]+B[7])*inv);
  Dn[1152] = __float2half((B[8]-lamb)*inv);
}

// ---------------------------------------------------------------------------
// Final: out = Xn + reconstruct(Tb)
// ---------------------------------------------------------------------------
__global__ __launch_bounds__(256) void k_final(
    const __half* __restrict__ Xn, const __half* __restrict__ Tb,
    float* __restrict__ out)
{
  int idx = blockIdx.x*256 + threadIdx.x;
  int n = idx >> 7, o = idx & 127;
  const __half* Tc = &Tb[(size_t)n*1280 + o];
  float lam=(float)Tc[0], a0=(float)Tc[128], a1=(float)Tc[256], a2=(float)Tc[384];
  float s00=(float)Tc[512], s01=(float)Tc[640], s02=(float)Tc[768];
  float s11=(float)Tc[896], s12=(float)Tc[1024], s22=(float)Tc[1152];
  const __half* xc = &Xn[(size_t)n*1152 + o*9];
  float* oc = &out[(size_t)n*1152 + o*9];
  oc[0] = (float)xc[0] + lam + s00;
  oc[1] = (float)xc[1] + a0  + s01;
  oc[2] = (float)xc[2] + a1  + s02;
  oc[3] = (float)xc[3] - a0  + s01;
  oc[4] = (float)xc[4] + lam + s11;
  oc[5] = (float)xc[5] + a2  + s12;
  oc[6] = (float)xc[6] - a1  + s02;
  oc[7] = (float)xc[7] - a2  + s12;
  oc[8] = (float)xc[8] + lam + s22;
}

// ---------------------------------------------------------------------------
extern "C" void kernel_launch(void* const* d_in, const int* in_sizes, int n_in,
                              void* d_out, int out_size, void* d_ws, size_t ws_size,
                              hipStream_t stream)
{
  const float* X     = (const float*)d_in[0];
  const float* ew    = (const float*)d_in[1];
  const float* eattr = (const float*)d_in[2];
  const float* Wp    = (const float*)d_in[3];
  const float* bp    = (const float*)d_in[4];
  const float* Ws0   = (const float*)d_in[5];
  const float* bs0   = (const float*)d_in[6];
  const float* Ws1   = (const float*)d_in[7];
  const float* bs1   = (const float*)d_in[8];
  const float* Ws2   = (const float*)d_in[9];
  const float* bs2   = (const float*)d_in[10];
  const int*   eidx  = (const int*)d_in[11];
  const float* Wt0   = (const float*)d_in[12];
  const float* Wt1   = (const float*)d_in[13];
  const float* Wt2   = (const float*)d_in[14];
  const float* Wt3   = (const float*)d_in[15];
  const float* Wt4   = (const float*)d_in[16];
  const float* Wt5   = (const float*)d_in[17];
  float* out = (float*)d_out;

  // Packed lifetime-aliased layout, peak 255,096,832 B:
  //  A [0,          23,040,000)  Xn fp16                  [node_post -> final]
  //  B [23,040,000, 48,640,000)  T1 fp16 -> D2 (in-place) [K2 -> K4]
  //  C [48,640,000, 130,560,000) {D1 | Xt | Xp} -> h1 -> msg -> Tb
  //  D [130,560,000,253,440,000) h0 -> ea_s               (122.88 MB)
  //  csr [253,440,000, 254,801,920)  off, cur, inv, dst_s
  //  Wfl [254,801,920, 255,096,832)  frag-linear fp16 Wp, Ws1, Ws2
  const size_t NEED = 255096832;
  if (ws_size < NEED) return;   // diagnostic: poison-fail instead of fault

  char* base = (char*)d_ws;
  __half*   Xn  = (__half*)(base);
  __half*   T1  = (__half*)(base + 23040000);
  __half*   D1  = (__half*)(base + 48640000);          // 25.6 MB [node_post -> K2]
  _Float16* Xt  = (_Float16*)(base + 74240000);        // 23.04 MB [pre -> gemm]
  _Float16* Xp  = (_Float16*)(base + 97280000);        // 23.04 MB [gemm -> post]
  __half*   h1  = (__half*)(base + 48640000);
  __half*   msg = (__half*)(base + 48640000);
  __half*   Tb  = (__half*)(base + 48640000);
  __half*   h0  = (__half*)(base + 130560000);
  __half*   ea  = (__half*)(base + 130560000);
  int* off_  = (int*)(base + 253440000);               // 40960 B
  int* cur_  = (int*)(base + 253480960);               // 40960 B
  int* inv_  = (int*)(base + 253521920);               // 640000 B
  int* dst_s = (int*)(base + 254161920);               // 640000 B
  _Float16* W0fl = (_Float16*)(base + 254801920);      // 32768 B
  _Float16* W1fl = (_Float16*)(base + 254834688);      // 65536 B
  _Float16* W2fl = (_Float16*)(base + 254900224);      // 196608 B

  (void)in_sizes; (void)n_in; (void)out_size;

  // CSR over src (needed by G3's rowmap) — run first
  k_zero_i<<<40, 256, 0, stream>>>(cur_, NN);
  k_hist<<<625, 256, 0, stream>>>(eidx, cur_);
  k_scan<<<1, 1024, 0, stream>>>(cur_, off_, cur_);
  k_scatter<<<625, 256, 0, stream>>>(eidx, eidx + EE, cur_, inv_, dst_s);

  // weight pre-pack (frag-linear fp16) for the pipelined GEMMs
  k_wprep<<<8, 256, 0, stream>>>(Wp, W0fl, 128, 128);
  k_wprep<<<16, 256, 0, stream>>>(Ws1, W1fl, 256, 128);
  k_wprep<<<48, 256, 0, stream>>>(Ws2, W2fl, 384, 256);

  // node phase: pack -> pipelined MFMA GEMM (M=90000,K=128,N=128) -> norm/decompose
  k_node_pre<<<2500, 256, 0, stream>>>(X, Xt);
  k_gemm_pipe<128, false, false><<<704, 256, 0, stream>>>(
      Xt, W0fl, bp, nullptr, nullptr, Xp, 128, 9*NN, 1);
  k_node_post<<<5000, 256, 0, stream>>>(Xp, Xn, D1);

  // T' = clin(I,Wt0)/clin(A,Wt1)/clin(S,Wt2): 10 slices of [10000 x 128 x 128]
  k_gemm_mfma<_Float16, 128, false, false, true><<<dim3(40*2, 1, 10), 256, 0, stream>>>(
      (_Float16*)D1, 1280, Wt0, Wt1, Wt2, nullptr, nullptr, (_Float16*)T1, 1280, NN, 2);

  // edge MLP: layer1 (mfma, f32 A), layers 2-3 pipelined; G3 writes CSR-ordered
  k_gemm_mfma<float, 32, true, false, false><<<dim3(625*2, 1, 1), 256, 0, stream>>>(
      eattr, 32, Ws0, nullptr, nullptr, bs0, nullptr, (_Float16*)h0, 128, EE, 2);
  k_gemm_pipe<128, true, false><<<2500, 256, 0, stream>>>(
      (_Float16*)h0, W1fl, bs1, nullptr, nullptr, (_Float16*)h1, 256, EE, 2);
  k_gemm_pipe<256, true, true><<<3750, 256, 0, stream>>>(
      (_Float16*)h1, W2fl, bs2, ew, inv_, (_Float16*)ea, 384, EE, 3);

  // message passing: sequential ea_s stream + L3-resident T1 gather
  k_message<<<5000, 256, 0, stream>>>(ea, T1, dst_s, off_, msg);

  // bracket + decompose + norm (D2 overwrites T1 in-place)
  k_bracket<<<5000, 256, 0, stream>>>(msg, T1, T1);

  // dX components = clin with Wt3/4/5
  k_gemm_mfma<_Float16, 128, false, false, true><<<dim3(40*2, 1, 10), 256, 0, stream>>>(
      (_Float16*)T1, 1280, Wt3, Wt4, Wt5, nullptr, nullptr, (_Float16*)Tb, 1280, NN, 2);

  // out = Xn + reconstruct(dX)
  k_final<<<5000, 256, 0, stream>>>(Xn, Tb, out);
}

// Round 8
// 368.723 us; speedup vs baseline: 1.2506x; 1.0362x over previous
//
#include <hip/hip_runtime.h>
#include <hip/hip_fp16.h>
#include <type_traits>

#define NN 10000
#define EE 160000

typedef _Float16 half8 __attribute__((ext_vector_type(8)));
typedef float    f32x4 __attribute__((ext_vector_type(4)));

// ---------------------------------------------------------------------------
// Node phase:
//  pre : Xt[(n,ij)][c] fp16  <- X[n][c][ij] f32      (pack/transpose)
//  gemm: Xp[(n,ij)][o] = sum_c Xt * Wp[o][c] + bp[o] (k_gemm_pipe)
//  post: per (n,o): norm over 9 ij, decompose -> Xn[n][o][ij], D1[n][10][128]
// ---------------------------------------------------------------------------
__global__ __launch_bounds__(256) void k_node_pre(
    const float* __restrict__ X, _Float16* __restrict__ Xt)
{
  __shared__ float Xl[4*1152];
  const int n0 = blockIdx.x * 4;
  const int t = threadIdx.x;
  const float* src = X + (size_t)n0*1152;
  #pragma unroll
  for (int idx = t; idx < 4*1152; idx += 256) Xl[idx] = src[idx];
  __syncthreads();
  _Float16* dst = Xt + (size_t)n0*1152;
  #pragma unroll
  for (int idx = t; idx < 4*1152; idx += 256) {
    int node = idx / 1152, rem = idx - node*1152;
    int ij = rem >> 7, c = rem & 127;
    dst[idx] = (_Float16)Xl[node*1152 + c*9 + ij];   // stride-9 LDS: odd -> conflict-free
  }
}

__global__ __launch_bounds__(256) void k_node_post(
    const _Float16* __restrict__ Xp,
    __half* __restrict__ Xn, __half* __restrict__ D1)
{
  int idx = blockIdx.x*256 + threadIdx.x;
  int n = idx >> 7, o = idx & 127;
  float m[9], ss = 0.f;
  #pragma unroll
  for (int ij = 0; ij < 9; ++ij) {
    m[ij] = (float)Xp[((size_t)n*9 + ij)*128 + o];   // coalesced across o
    ss += m[ij]*m[ij];
  }
  ss = fmaxf(ss, 0.01f);
  float inv = 1.f / (ss + 1.f);
  #pragma unroll
  for (int ij = 0; ij < 9; ++ij) m[ij] *= inv;
  __half* xo = &Xn[(size_t)n*1152 + o*9];
  #pragma unroll
  for (int ij = 0; ij < 9; ++ij) xo[ij] = __float2half(m[ij]);
  float lam = (m[0]+m[4]+m[8]) * (1.f/3.f);
  __half* Dn = &D1[(size_t)n*1280];
  Dn[0*128+o] = __float2half(lam);
  Dn[1*128+o] = __float2half(0.5f*(m[1]-m[3]));
  Dn[2*128+o] = __float2half(0.5f*(m[2]-m[6]));
  Dn[3*128+o] = __float2half(0.5f*(m[5]-m[7]));
  Dn[4*128+o] = __float2half(m[0]-lam);
  Dn[5*128+o] = __float2half(0.5f*(m[1]+m[3]));
  Dn[6*128+o] = __float2half(0.5f*(m[2]+m[6]));
  Dn[7*128+o] = __float2half(m[4]-lam);
  Dn[8*128+o] = __float2half(0.5f*(m[5]+m[7]));
  Dn[9*128+o] = __float2half(m[8]-lam);
}

// ---------------------------------------------------------------------------
// Weight pre-pack (all three pipelined-GEMM weights in ONE launch):
//   Wfl[((kc*(N/16) + nf)*64 + lane)*8 + j] = W[nf*16+(lane&15)][kc*32+(lane>>4)*8+j]
// ---------------------------------------------------------------------------
__device__ __forceinline__ void wprep_one(
    const float* __restrict__ W, _Float16* __restrict__ Wfl, int N, int K, int u)
{
  int lane = u & 63, rest = u >> 6;
  int nfTotal = N >> 4;
  int nf = rest % nfTotal, kc = rest / nfTotal;
  int n = nf*16 + (lane & 15);
  int k = kc*32 + (lane >> 4)*8;
  const float* src = W + (size_t)n*K + k;
  half8 hv;
  #pragma unroll
  for (int j = 0; j < 8; ++j) hv[j] = (_Float16)src[j];
  *reinterpret_cast<half8*>(Wfl + (size_t)u*8) = hv;
}
__global__ __launch_bounds__(256) void k_wprep3(
    const float* __restrict__ Wp, const float* __restrict__ Ws1,
    const float* __restrict__ Ws2,
    _Float16* __restrict__ W0fl, _Float16* __restrict__ W1fl,
    _Float16* __restrict__ W2fl)
{
  int u = blockIdx.x*256 + threadIdx.x;
  if (u < 2048)       wprep_one(Wp,  W0fl, 128, 128, u);
  else if (u < 6144)  wprep_one(Ws1, W1fl, 256, 128, u - 2048);
  else if (u < 18432) wprep_one(Ws2, W2fl, 384, 256, u - 6144);
}

// ---------------------------------------------------------------------------
// Pipelined MFMA GEMM (m97 structure): C[m][n] = post(sum_k A[m][k]*W[n][k]+b[n])
//   - BM=128, BN=128, BK=32, 4 waves; wave owns 32 rows x 128 cols (acc[2][8])
//   - A and W double-buffered via global_load_lds width-16 DMA
//   - A LDS seg pre-swizzled seg^(row&3) at source; read seg = lq^(lr&3)
//   - rowmap (optional): output row permutation (CSR-ordered ea write)
// ---------------------------------------------------------------------------
template<int KT, bool ACT, bool CUT>
__global__ __launch_bounds__(256, 4) void k_gemm_pipe(
    const _Float16* __restrict__ A,
    const _Float16* __restrict__ Wfl,
    const float* __restrict__ bias, const float* __restrict__ cw,
    const int* __restrict__ rowmap,
    _Float16* __restrict__ C, int ldc,
    int M, int nTiles)
{
  constexpr int NC = KT / 32;
  __shared__ _Float16 Abuf[2][128*32];
  __shared__ _Float16 Wbuf[2][128*32];
  const int t = threadIdx.x;
  const int nfTotal = nTiles * 8;

  int nwg = gridDim.x, bid = blockIdx.x;
  int q = nwg >> 3, rr = nwg & 7;
  int xcd = bid & 7, ii = bid >> 3;
  int swz = (xcd < rr) ? xcd*(q+1) + ii : rr*(q+1) + (xcd-rr)*q + ii;
  int nt = swz % nTiles, mt = swz / nTiles;
  const int n0 = nt * 128, m0 = mt * 128;

  auto stage = [&](int d, int kc) {
    #pragma unroll
    for (int i = 0; i < 2; ++i) {
      int u = t + i*256;
      int row = u >> 2, seg = u & 3;
      int gm = m0 + row; if (gm > M-1) gm = M-1;
      const _Float16* gp = A + (size_t)gm*KT + kc*32 + ((seg ^ (row & 3)) << 3);
      __builtin_amdgcn_global_load_lds(
          (const __attribute__((address_space(1))) _Float16*)gp,
          (__attribute__((address_space(3))) _Float16*)(&Abuf[d][u*8]), 16, 0, 0);
    }
    const _Float16* wp = Wfl + (((size_t)kc*nfTotal + nt*8) << 9);
    #pragma unroll
    for (int i = 0; i < 2; ++i) {
      int u = t + i*256;
      __builtin_amdgcn_global_load_lds(
          (const __attribute__((address_space(1))) _Float16*)(wp + u*8),
          (__attribute__((address_space(3))) _Float16*)(&Wbuf[d][u*8]), 16, 0, 0);
    }
  };

  const int wave = t >> 6, lane = t & 63;
  const int lr = lane & 15, lq = lane >> 4;
  const int wrow = wave * 32;
  const int aoff = (lq ^ (lr & 3)) << 3;

  f32x4 acc[2][8] = {};

  stage(0, 0);
  __syncthreads();
  int cur = 0;
  for (int kc = 0; kc < NC; ++kc) {
    if (kc + 1 < NC) stage(cur ^ 1, kc + 1);
    const _Float16* ab = &Abuf[cur][0];
    const _Float16* wb = &Wbuf[cur][0];
    half8 a0 = *reinterpret_cast<const half8*>(ab + (wrow + lr)*32 + aoff);
    half8 a1 = *reinterpret_cast<const half8*>(ab + (wrow + 16 + lr)*32 + aoff);
    #pragma unroll
    for (int c = 0; c < 8; ++c) {
      half8 b = *reinterpret_cast<const half8*>(wb + c*512 + lane*8);
      acc[0][c] = __builtin_amdgcn_mfma_f32_16x16x32_f16(a0, b, acc[0][c], 0, 0, 0);
      acc[1][c] = __builtin_amdgcn_mfma_f32_16x16x32_f16(a1, b, acc[1][c], 0, 0, 0);
    }
    if (kc + 1 < NC) { __syncthreads(); cur ^= 1; }
  }

  float bvv[8];
  #pragma unroll
  for (int c = 0; c < 8; ++c) bvv[c] = bias[n0 + c*16 + lr];
  #pragma unroll
  for (int r = 0; r < 2; ++r) {
    #pragma unroll
    for (int j = 0; j < 4; ++j) {
      int gm = m0 + wrow + r*16 + lq*4 + j;   // C/D: col=lane&15, row=(lane>>4)*4+reg
      if (gm >= M) continue;
      float Cf = 1.f;
      if (CUT) {
        float wv = cw[gm];
        Cf = (wv < 5.f) ? 0.5f*(__cosf(wv*0.62831853071795864769f) + 1.f) : 0.f;
      }
      int orow = rowmap ? rowmap[gm] : gm;
      _Float16* crow = C + (size_t)orow*ldc + n0;
      #pragma unroll
      for (int c = 0; c < 8; ++c) {
        float v = acc[r][c][j] + bvv[c];
        if (ACT) v = v / (1.f + __expf(-v));   // silu
        if (CUT) v *= Cf;
        crow[c*16 + lr] = (_Float16)v;
      }
    }
  }
}

// ---------------------------------------------------------------------------
// MFMA GEMM (non-pipelined; small/odd-shaped GEMMs):
//   BM=256, BN=64; W staged fp32->fp16 fragment-linear LDS (conflict-free)
//   PSEL: blockIdx.z = p in 0..9: W = p==0?W0 : p<4?W1 : W2; A,C col-offset p*128
// ---------------------------------------------------------------------------
template<typename TA, int KT, bool ACT, bool CUT, bool PSEL>
__global__ __launch_bounds__(256) void k_gemm_mfma(
    const TA* __restrict__ A, int lda,
    const float* __restrict__ W0, const float* __restrict__ W1, const float* __restrict__ W2,
    const float* __restrict__ bias, const float* __restrict__ cw,
    _Float16* __restrict__ C, int ldc,
    int M, int nTiles)
{
  constexpr int NFRAG = (KT/32)*4;
  __shared__ _Float16 Bs[NFRAG*64*8];
  const int t = threadIdx.x;

  int nwg = gridDim.x;
  int bid = blockIdx.x;
  int q = nwg >> 3, rr = nwg & 7;
  int xcd = bid & 7, ii = bid >> 3;
  int swz = (xcd < rr) ? xcd*(q+1) + ii : rr*(q+1) + (xcd-rr)*q + ii;
  int nt = swz % nTiles;
  int mt = swz / nTiles;

  const float* W = W0;
  int coff = 0;
  if (PSEL) {
    int p = blockIdx.z;
    W = (p == 0) ? W0 : (p < 4 ? W1 : W2);
    coff = p * 128;
  }
  const int n0 = nt * 64;
  const int m0 = mt * 256;

  #pragma unroll
  for (int u = t; u < NFRAG*64; u += 256) {
    int g = u >> 6, lu = u & 63;
    int lru = lu & 15, lqu = lu >> 4;
    int nn = (g & 3)*16 + lru;
    int kk = (g >> 2)*32 + lqu*8;
    const float* wp = &W[(size_t)(n0 + nn)*KT + kk];
    f32x4 w0 = *reinterpret_cast<const f32x4*>(wp);
    f32x4 w1 = *reinterpret_cast<const f32x4*>(wp + 4);
    half8 hv;
    #pragma unroll
    for (int j = 0; j < 4; ++j) { hv[j] = (_Float16)w0[j]; hv[4+j] = (_Float16)w1[j]; }
    *reinterpret_cast<half8*>(&Bs[u*8]) = hv;
  }
  __syncthreads();

  const int wave = t >> 6, lane = t & 63;
  const int lr = lane & 15, lq = lane >> 4;
  const int rowBase = m0 + wave*64;
  const int kBase = lq*8;

  const TA* aptr[4];
  #pragma unroll
  for (int r = 0; r < 4; ++r) {
    int gm = rowBase + r*16 + lr;
    if (gm > M-1) gm = M-1;
    aptr[r] = A + (size_t)gm*lda + coff + kBase;
  }

  f32x4 acc[4][4] = {};
  #pragma unroll
  for (int k0 = 0; k0 < KT; k0 += 32) {
    half8 b[4];
    #pragma unroll
    for (int c = 0; c < 4; ++c)
      b[c] = *reinterpret_cast<const half8*>(&Bs[(((k0>>5)<<2) + c)*512 + lane*8]);
    half8 a[4];
    #pragma unroll
    for (int r = 0; r < 4; ++r) {
      const TA* ap = aptr[r] + k0;
      if constexpr (std::is_same<TA, float>::value) {
        f32x4 u0 = *reinterpret_cast<const f32x4*>(ap);
        f32x4 u1 = *reinterpret_cast<const f32x4*>(ap + 4);
        half8 av;
        #pragma unroll
        for (int j = 0; j < 4; ++j) { av[j] = (_Float16)u0[j]; av[4+j] = (_Float16)u1[j]; }
        a[r] = av;
      } else {
        a[r] = *reinterpret_cast<const half8*>(ap);
      }
    }
    #pragma unroll
    for (int r = 0; r < 4; ++r)
      #pragma unroll
      for (int c = 0; c < 4; ++c)
        acc[r][c] = __builtin_amdgcn_mfma_f32_16x16x32_f16(a[r], b[c], acc[r][c], 0, 0, 0);
  }

  float bvv[4];
  #pragma unroll
  for (int c = 0; c < 4; ++c)
    bvv[c] = bias ? bias[n0 + c*16 + lr] : 0.f;
  #pragma unroll
  for (int r = 0; r < 4; ++r) {
    #pragma unroll
    for (int j = 0; j < 4; ++j) {
      int gm = rowBase + r*16 + lq*4 + j;
      if (gm >= M) continue;
      float Cf = 1.f;
      if (CUT) {
        float wv = cw[gm];
        Cf = (wv < 5.f) ? 0.5f*(__cosf(wv*0.62831853071795864769f) + 1.f) : 0.f;
      }
      _Float16* crow = C + (size_t)gm*ldc + coff + n0;
      #pragma unroll
      for (int c = 0; c < 4; ++c) {
        float v = acc[r][c][j] + bvv[c];
        if (ACT) v = v / (1.f + __expf(-v));
        if (CUT) v *= Cf;
        crow[c*16 + lr] = (_Float16)v;
      }
    }
  }
}

// ---------------------------------------------------------------------------
// CSR build over src. Scatter also emits inv[e]=pos and dst_s[pos]=dst[e].
// ---------------------------------------------------------------------------
__global__ void k_zero_i(int* __restrict__ p, int n) {
  int i = blockIdx.x*256 + threadIdx.x;
  if (i < n) p[i] = 0;
}
__global__ void k_hist(const int* __restrict__ src, int* __restrict__ cnt) {
  int e = blockIdx.x*256 + threadIdx.x;
  if (e < EE) atomicAdd(&cnt[src[e]], 1);
}
__global__ __launch_bounds__(1024) void k_scan(const int* __restrict__ cnt,
                                               int* __restrict__ off,
                                               int* __restrict__ cur) {
  __shared__ int s[1024];
  __shared__ int carry;
  int t = threadIdx.x;
  if (t == 0) carry = 0;
  __syncthreads();
  for (int base = 0; base < NN; base += 1024) {
    int i = base + t;
    int v = (i < NN) ? cnt[i] : 0;
    s[t] = v; __syncthreads();
    for (int d = 1; d < 1024; d <<= 1) {
      int x = (t >= d) ? s[t-d] : 0; __syncthreads();
      s[t] += x; __syncthreads();
    }
    int incl = s[t];
    int total = s[1023];
    int excl = incl - v + carry;
    if (i < NN) { off[i] = excl; cur[i] = excl; }
    __syncthreads();
    if (t == 0) carry += total;
    __syncthreads();
  }
  if (t == 0) off[NN] = carry;
}
__global__ void k_scatter(const int* __restrict__ src, const int* __restrict__ dst,
                          int* __restrict__ cur,
                          int* __restrict__ inv, int* __restrict__ dst_s) {
  int e = blockIdx.x*256 + threadIdx.x;
  if (e < EE) {
    int pos = atomicAdd(&cur[src[e]], 1);
    inv[e] = pos;
    dst_s[pos] = dst[e];
  }
}

// ---------------------------------------------------------------------------
// Fused message + bracket:
//  - 4 nodes/block, 1 wave/node, lane l owns o-pair (2l, 2l+1)
//  - msg accumulated in regs (f32); then B = M*Y+Y*M, decompose, /(tnorm+1)
//  - D2 written to a DIFFERENT buffer than T1 (other blocks still gather T1)
//  - ea_s is CSR-ordered: sequential stream; T1 gather via scalar dst base
// ---------------------------------------------------------------------------
__device__ __forceinline__ void bracket10(
    const float* __restrict__ M, const float* __restrict__ Y,
    float* __restrict__ D)
{
  float Mm[9], Ym[9];
  Mm[0]=M[0]+M[4]; Mm[1]=M[1]+M[5]; Mm[2]=M[2]+M[6];
  Mm[3]=M[5]-M[1]; Mm[4]=M[0]+M[7]; Mm[5]=M[3]+M[8];
  Mm[6]=M[6]-M[2]; Mm[7]=M[8]-M[3]; Mm[8]=M[0]+M[9];
  Ym[0]=Y[0]+Y[4]; Ym[1]=Y[1]+Y[5]; Ym[2]=Y[2]+Y[6];
  Ym[3]=Y[5]-Y[1]; Ym[4]=Y[0]+Y[7]; Ym[5]=Y[3]+Y[8];
  Ym[6]=Y[6]-Y[2]; Ym[7]=Y[8]-Y[3]; Ym[8]=Y[0]+Y[9];
  float B[9];
  #pragma unroll
  for (int i = 0; i < 3; ++i)
    #pragma unroll
    for (int j = 0; j < 3; ++j) {
      float s = 0.f;
      #pragma unroll
      for (int k = 0; k < 3; ++k)
        s += Mm[i*3+k]*Ym[k*3+j] + Ym[i*3+k]*Mm[k*3+j];
      B[i*3+j] = s;
    }
  float lamb = (B[0]+B[4]+B[8]) * (1.f/3.f);
  float ss = 0.f;
  #pragma unroll
  for (int qq = 0; qq < 9; ++qq) ss += B[qq]*B[qq];
  float inv = 1.f / (fmaxf(ss, 0.01f) + 1.f);
  D[0] = lamb*inv;
  D[1] = 0.5f*(B[1]-B[3])*inv;
  D[2] = 0.5f*(B[2]-B[6])*inv;
  D[3] = 0.5f*(B[5]-B[7])*inv;
  D[4] = (B[0]-lamb)*inv;
  D[5] = 0.5f*(B[1]+B[3])*inv;
  D[6] = 0.5f*(B[2]+B[6])*inv;
  D[7] = (B[4]-lamb)*inv;
  D[8] = 0.5f*(B[5]+B[7])*inv;
  D[9] = (B[8]-lamb)*inv;
}

__global__ __launch_bounds__(256) void k_msgbr(
    const __half* __restrict__ ea_s, const __half* __restrict__ T1,
    const int* __restrict__ dst_s, const int* __restrict__ off,
    __half* __restrict__ D2)
{
  const int t = threadIdx.x;
  const int l = t & 63;
  const int wv = __builtin_amdgcn_readfirstlane(t >> 6);
  const int n = blockIdx.x*4 + wv;
  const int e0 = __builtin_amdgcn_readfirstlane(off[n]);
  const int e1 = __builtin_amdgcn_readfirstlane(off[n+1]);

  float a0[10] = {}, a1[10] = {};   // msg for o0=2l and o1=2l+1
  auto edge = [&](int ii) {
    int d = __builtin_amdgcn_readfirstlane(dst_s[ii]);
    const __half2* fe = (const __half2*)(ea_s + (size_t)ii*384 + 6*l);
    float2 q0 = __half22float2(fe[0]);   // f0(o0), f1(o0)
    float2 q1 = __half22float2(fe[1]);   // f2(o0), f0(o1)
    float2 q2 = __half22float2(fe[2]);   // f1(o1), f2(o1)
    const __half2* Td = (const __half2*)(T1 + (size_t)d*1280) + l;
    float2 tc;
    tc = __half22float2(Td[0]);    a0[0] += q0.x*tc.x; a1[0] += q1.y*tc.y;
    tc = __half22float2(Td[64]);   a0[1] += q0.y*tc.x; a1[1] += q2.x*tc.y;
    tc = __half22float2(Td[128]);  a0[2] += q0.y*tc.x; a1[2] += q2.x*tc.y;
    tc = __half22float2(Td[192]);  a0[3] += q0.y*tc.x; a1[3] += q2.x*tc.y;
    #pragma unroll
    for (int c = 4; c < 10; ++c) {
      tc = __half22float2(Td[c*64]);
      a0[c] += q1.x*tc.x; a1[c] += q2.y*tc.y;
    }
  };
  int ii = e0;
  for (; ii + 2 <= e1; ii += 2) { edge(ii); edge(ii+1); }
  if (ii < e1) edge(ii);

  // own node's Y row
  const __half2* Yd = (const __half2*)(T1 + (size_t)n*1280) + l;
  float y0[10], y1[10];
  #pragma unroll
  for (int c = 0; c < 10; ++c) {
    float2 yc = __half22float2(Yd[c*64]);
    y0[c] = yc.x; y1[c] = yc.y;
  }
  float d0[10], d1[10];
  bracket10(a0, y0, d0);
  bracket10(a1, y1, d1);
  __half2* Dn = (__half2*)(D2 + (size_t)n*1280) + l;
  #pragma unroll
  for (int c = 0; c < 10; ++c)
    Dn[c*64] = __floats2half2_rn(d0[c], d1[c]);
}

// ---------------------------------------------------------------------------
// Final: out = Xn + reconstruct(Tb)
// ---------------------------------------------------------------------------
__global__ __launch_bounds__(256) void k_final(
    const __half* __restrict__ Xn, const __half* __restrict__ Tb,
    float* __restrict__ out)
{
  int idx = blockIdx.x*256 + threadIdx.x;
  int n = idx >> 7, o = idx & 127;
  const __half* Tc = &Tb[(size_t)n*1280 + o];
  float lam=(float)Tc[0], a0=(float)Tc[128], a1=(float)Tc[256], a2=(float)Tc[384];
  float s00=(float)Tc[512], s01=(float)Tc[640], s02=(float)Tc[768];
  float s11=(float)Tc[896], s12=(float)Tc[1024], s22=(float)Tc[1152];
  const __half* xc = &Xn[(size_t)n*1152 + o*9];
  float* oc = &out[(size_t)n*1152 + o*9];
  oc[0] = (float)xc[0] + lam + s00;
  oc[1] = (float)xc[1] + a0  + s01;
  oc[2] = (float)xc[2] + a1  + s02;
  oc[3] = (float)xc[3] - a0  + s01;
  oc[4] = (float)xc[4] + lam + s11;
  oc[5] = (float)xc[5] + a2  + s12;
  oc[6] = (float)xc[6] - a1  + s02;
  oc[7] = (float)xc[7] - a2  + s12;
  oc[8] = (float)xc[8] + lam + s22;
}

// ---------------------------------------------------------------------------
extern "C" void kernel_launch(void* const* d_in, const int* in_sizes, int n_in,
                              void* d_out, int out_size, void* d_ws, size_t ws_size,
                              hipStream_t stream)
{
  const float* X     = (const float*)d_in[0];
  const float* ew    = (const float*)d_in[1];
  const float* eattr = (const float*)d_in[2];
  const float* Wp    = (const float*)d_in[3];
  const float* bp    = (const float*)d_in[4];
  const float* Ws0   = (const float*)d_in[5];
  const float* bs0   = (const float*)d_in[6];
  const float* Ws1   = (const float*)d_in[7];
  const float* bs1   = (const float*)d_in[8];
  const float* Ws2   = (const float*)d_in[9];
  const float* bs2   = (const float*)d_in[10];
  const int*   eidx  = (const int*)d_in[11];
  const float* Wt0   = (const float*)d_in[12];
  const float* Wt1   = (const float*)d_in[13];
  const float* Wt2   = (const float*)d_in[14];
  const float* Wt3   = (const float*)d_in[15];
  const float* Wt4   = (const float*)d_in[16];
  const float* Wt5   = (const float*)d_in[17];
  float* out = (float*)d_out;

  // Packed lifetime-aliased layout, peak 255,096,832 B:
  //  A [0,          23,040,000)  Xn fp16                  [node_post -> final]
  //  B [23,040,000, 48,640,000)  T1 fp16 [K2 -> msgbr] -> Tb [K4 -> final]
  //  C [48,640,000, 130,560,000) {D1 | Xt | Xp} -> h1 -> D2 [msgbr -> K4]
  //  D [130,560,000,253,440,000) h0 -> ea_s               (122.88 MB)
  //  csr [253,440,000, 254,801,920)  off, cur, inv, dst_s
  //  Wfl [254,801,920, 255,096,832)  frag-linear fp16 Wp, Ws1, Ws2
  const size_t NEED = 255096832;
  if (ws_size < NEED) return;   // diagnostic: poison-fail instead of fault

  char* base = (char*)d_ws;
  __half*   Xn  = (__half*)(base);
  __half*   T1  = (__half*)(base + 23040000);
  __half*   Tb  = (__half*)(base + 23040000);          // reuses T1 (dead after msgbr)
  __half*   D1  = (__half*)(base + 48640000);          // 25.6 MB [node_post -> K2]
  _Float16* Xt  = (_Float16*)(base + 74240000);        // 23.04 MB [pre -> gemm]
  _Float16* Xp  = (_Float16*)(base + 97280000);        // 23.04 MB [gemm -> post]
  __half*   h1  = (__half*)(base + 48640000);
  __half*   D2  = (__half*)(base + 48640000);          // msgbr output [-> K4]
  __half*   h0  = (__half*)(base + 130560000);
  __half*   ea  = (__half*)(base + 130560000);
  int* off_  = (int*)(base + 253440000);               // 40960 B
  int* cur_  = (int*)(base + 253480960);               // 40960 B
  int* inv_  = (int*)(base + 253521920);               // 640000 B
  int* dst_s = (int*)(base + 254161920);               // 640000 B
  _Float16* W0fl = (_Float16*)(base + 254801920);      // 32768 B
  _Float16* W1fl = (_Float16*)(base + 254834688);      // 65536 B
  _Float16* W2fl = (_Float16*)(base + 254900224);      // 196608 B

  (void)in_sizes; (void)n_in; (void)out_size;

  // CSR over src (needed by G3's rowmap) — run first
  k_zero_i<<<40, 256, 0, stream>>>(cur_, NN);
  k_hist<<<625, 256, 0, stream>>>(eidx, cur_);
  k_scan<<<1, 1024, 0, stream>>>(cur_, off_, cur_);
  k_scatter<<<625, 256, 0, stream>>>(eidx, eidx + EE, cur_, inv_, dst_s);

  // weight pre-pack (one launch)
  k_wprep3<<<72, 256, 0, stream>>>(Wp, Ws1, Ws2, W0fl, W1fl, W2fl);

  // node phase: pack -> pipelined MFMA GEMM (M=90000,K=128,N=128) -> norm/decompose
  k_node_pre<<<2500, 256, 0, stream>>>(X, Xt);
  k_gemm_pipe<128, false, false><<<704, 256, 0, stream>>>(
      Xt, W0fl, bp, nullptr, nullptr, Xp, 128, 9*NN, 1);
  k_node_post<<<5000, 256, 0, stream>>>(Xp, Xn, D1);

  // T' = clin(I,Wt0)/clin(A,Wt1)/clin(S,Wt2): 10 slices of [10000 x 128 x 128]
  k_gemm_mfma<_Float16, 128, false, false, true><<<dim3(40*2, 1, 10), 256, 0, stream>>>(
      (_Float16*)D1, 1280, Wt0, Wt1, Wt2, nullptr, nullptr, (_Float16*)T1, 1280, NN, 2);

  // edge MLP: layer1 (mfma, f32 A), layers 2-3 pipelined; G3 writes CSR-ordered
  k_gemm_mfma<float, 32, true, false, false><<<dim3(625*2, 1, 1), 256, 0, stream>>>(
      eattr, 32, Ws0, nullptr, nullptr, bs0, nullptr, (_Float16*)h0, 128, EE, 2);
  k_gemm_pipe<128, true, false><<<2500, 256, 0, stream>>>(
      (_Float16*)h0, W1fl, bs1, nullptr, nullptr, (_Float16*)h1, 256, EE, 2);
  k_gemm_pipe<256, true, true><<<3750, 256, 0, stream>>>(
      (_Float16*)h1, W2fl, bs2, ew, inv_, (_Float16*)ea, 384, EE, 3);

  // fused message + bracket: D2 -> region C (T1 stays intact during gather)
  k_msgbr<<<2500, 256, 0, stream>>>(ea, T1, dst_s, off_, D2);

  // dX components = clin with Wt3/4/5 (reads D2 in C, writes Tb in B)
  k_gemm_mfma<_Float16, 128, false, false, true><<<dim3(40*2, 1, 10), 256, 0, stream>>>(
      (_Float16*)D2, 1280, Wt3, Wt4, Wt5, nullptr, nullptr, (_Float16*)Tb, 1280, NN, 2);

  // out = Xn + reconstruct(dX)
  k_final<<<5000, 256, 0, stream>>>(Xn, Tb, out);
}